// Round 3
// baseline (3535.332 us; speedup 1.0000x reference)
//
#include <hip/hip_runtime.h>
#include <cstdint>

typedef unsigned short bf16u;
typedef __attribute__((ext_vector_type(8))) short short8;
typedef __attribute__((ext_vector_type(4))) float f32x4;

#define SEQ   2048
#define EMB   2048
#define NHEAD 16
#define NKV   4
#define DKH   128
#define HIDN  8192
#define NVOC  32000
#define NLAY  4
#define WIN   1024
#define QKV_N 3072

__device__ __forceinline__ bf16u f2bf(float f) {
  union { float f; uint32_t u; } v; v.f = f;
  uint32_t r = v.u + 0x7FFFu + ((v.u >> 16) & 1u);
  return (bf16u)(r >> 16);
}

__device__ __forceinline__ void gl2lds16(const void* g, void* l) {
  __builtin_amdgcn_global_load_lds(
      (const __attribute__((address_space(1))) void*)g,
      (__attribute__((address_space(3))) void*)l, 16, 0, 0);
}

// ---------------- embedding ----------------
__global__ __launch_bounds__(256) void embed_kernel(const int* __restrict__ tokens,
                                                    const float* __restrict__ table,
                                                    float* __restrict__ x) {
  int s = blockIdx.x;
  int tok = tokens[s];
  int i0 = threadIdx.x * 8;
  float4 a = {0,0,0,0}, b = {0,0,0,0};
  if (tok != 0) {
    const float* src = table + (size_t)tok * EMB;
    a = *(const float4*)(src + i0);
    b = *(const float4*)(src + i0 + 4);
  }
  *(float4*)(x + (size_t)s * EMB + i0) = a;
  *(float4*)(x + (size_t)s * EMB + i0 + 4) = b;
}

// ---------------- rmsnorm (f32 in -> bf16 out) ----------------
__global__ __launch_bounds__(256) void rmsnorm_kernel(const float* __restrict__ x,
                                                      bf16u* __restrict__ out) {
  int s = blockIdx.x;
  const float* row = x + (size_t)s * EMB;
  int i0 = threadIdx.x * 8;
  float4 a = *(const float4*)(row + i0);
  float4 b = *(const float4*)(row + i0 + 4);
  float ss = a.x*a.x + a.y*a.y + a.z*a.z + a.w*a.w
           + b.x*b.x + b.y*b.y + b.z*b.z + b.w*b.w;
  #pragma unroll
  for (int off = 1; off < 64; off <<= 1) ss += __shfl_xor(ss, off);
  __shared__ float red[4];
  if ((threadIdx.x & 63) == 0) red[threadIdx.x >> 6] = ss;
  __syncthreads();
  float scale = rsqrtf((red[0] + red[1] + red[2] + red[3]) * (1.0f / EMB) + 1e-5f);
  float v[8] = {a.x, a.y, a.z, a.w, b.x, b.y, b.z, b.w};
  short8 o;
  #pragma unroll
  for (int j = 0; j < 8; ++j) o[j] = (short)f2bf(v[j] * scale);
  *(short8*)(out + (size_t)s * EMB + i0) = o;
}

// ---------------- transpose + f32->bf16 convert: in[R][C] -> out[C][R] ----------------
__global__ __launch_bounds__(256) void transp_kernel(const float* __restrict__ in,
                                                     bf16u* __restrict__ out,
                                                     int R, int C) {
  __shared__ float tile[32][33];
  int c0 = blockIdx.x * 32, r0 = blockIdx.y * 32;
  int tx = threadIdx.x & 31, ty = threadIdx.x >> 5;
  #pragma unroll
  for (int i = 0; i < 4; ++i)
    tile[ty + i * 8][tx] = in[(size_t)(r0 + ty + i * 8) * C + c0 + tx];
  __syncthreads();
  #pragma unroll
  for (int i = 0; i < 4; ++i)
    out[(size_t)(c0 + ty + i * 8) * R + r0 + tx] = f2bf(tile[tx][ty + i * 8]);
}

// ---------------- RoPE ----------------
__global__ __launch_bounds__(256) void rope_kernel(const float* __restrict__ qkv,
                                                   bf16u* __restrict__ out, int col0) {
  int idx = blockIdx.x * 256 + threadIdx.x;
  int d = idx & 63;
  int s = (idx >> 6) & (SEQ - 1);
  int h = idx >> 17;
  const float* row = qkv + (size_t)s * QKV_N + col0 + h * DKH;
  float ang = (float)s * __powf(10000.0f, -(float)d * (1.0f / 64.0f));
  float si, c;
  sincosf(ang, &si, &c);
  float f0 = row[d], f1 = row[d + 64];
  bf16u* orow = out + ((size_t)h * SEQ + s) * DKH;
  orow[d]      = f2bf(c * f0 - si * f1);
  orow[d + 64] = f2bf(c * f1 + si * f0);
}

__global__ __launch_bounds__(256) void vconv_kernel(const float* __restrict__ qkv,
                                                    bf16u* __restrict__ vout) {
  int idx = blockIdx.x * 256 + threadIdx.x;
  int d = idx & 127;
  int kv = (idx >> 7) & 3;
  int s = idx >> 9;
  vout[((size_t)kv * SEQ + s) * DKH + d] = f2bf(qkv[(size_t)s * QKV_N + 2560 + kv * DKH + d]);
}

// ---------------- swiglu ----------------
__global__ __launch_bounds__(256) void swiglu_kernel(const float* __restrict__ gu,
                                                     bf16u* __restrict__ h) {
  size_t idx = (size_t)blockIdx.x * 256 + threadIdx.x;
  int s = (int)(idx >> 13);
  int j = (int)(idx & 8191);
  float g = gu[(size_t)s * 16384 + j];
  float u = gu[(size_t)s * 16384 + 8192 + j];
  float sil = g / (1.0f + __expf(-g));
  h[idx] = f2bf(u * sil);
}

// ================= 256x256 8-phase GEMM (T1+T2+T3+T4+T5) =================
// C[M][N] = A[M][K] * Bt[N][K], bf16 in, f32 acc.
// 512 threads = 8 waves (2 M x 4 N). BK=64, 2 K-tiles per 8-phase iteration.
// LDS: 4 half-tile slots (128x64 bf16 = 16KB) per operand = 128 KiB.
//   Even K-tiles -> slots 0,1; odd -> slots 2,3 (ring, constant mapping).
// Swizzle: LDS[r][chunk] holds global chunk (chunk ^ (r&7)) (16B chunks),
//   realized via pre-swizzled global source (gl2lds dest stays linear).
// Stage schedule (phase p of iter I):
//   p0:A(2I+1,h1)->AS3  p1:B(2I+1,h0)->BS2  p2:B(2I+1,h1)->BS3
//   p3:A(2I+2,h0)->AS0  p4:A(2I+2,h1)->AS1  p5:B(2I+2,h0)->BS0
//   p6:B(2I+2,h1)->BS1  p7:A(2I+3,h0)->AS2
// Every stage is issued after the barrier ending the slot's last-read phase.
// vmcnt(2) at p3/p7 leaves exactly the newest half-tile in flight.

__device__ __forceinline__ void stage_half(const bf16u* __restrict__ p, int ld,
                                           int row0, int k0, char* slotBase, int t) {
  int r  = t >> 3, c8 = t & 7;
  int cs = (c8 ^ (r & 7)) << 3;           // pre-swizzled source chunk (elements)
  gl2lds16(p + (size_t)(row0 + r) * ld + k0 + cs, slotBase + t * 16);
  gl2lds16(p + (size_t)(row0 + 64 + r) * ld + k0 + cs, slotBase + 8192 + t * 16);
}

template<int KK>
__device__ __forceinline__ short8 read_frag(const char* slot, int row, int l4) {
  int kc = KK * 4 + l4;
  return *(const short8*)(slot + row * 128 + ((kc ^ (row & 7)) << 4));
}

template<int NH>
__device__ __forceinline__ void mfma_quad(f32x4 (&acc)[8][4], const short8 (&a)[8],
                                          short8 b0, short8 b1) {
  __builtin_amdgcn_s_setprio(1);
  #pragma unroll
  for (int mi = 0; mi < 8; ++mi) {
    acc[mi][NH * 2]     = __builtin_amdgcn_mfma_f32_16x16x32_bf16(a[mi], b0, acc[mi][NH * 2], 0, 0, 0);
    acc[mi][NH * 2 + 1] = __builtin_amdgcn_mfma_f32_16x16x32_bf16(a[mi], b1, acc[mi][NH * 2 + 1], 0, 0, 0);
  }
  __builtin_amdgcn_s_setprio(0);
}

template <int MODE>
__global__ __launch_bounds__(512) void gemm256_kernel(const bf16u* __restrict__ A,
                                                      const bf16u* __restrict__ Bt,
                                                      void* __restrict__ C,
                                                      int M, int N, int K) {
  __shared__ __align__(16) char lds[131072];

  int nx = gridDim.x, ny = gridDim.y;
  int nwg = nx * ny;
  int orig = blockIdx.y * nx + blockIdx.x;
  int q8 = nwg >> 3, r8 = nwg & 7;
  int xcd = orig & 7, loc = orig >> 3;
  int id = (xcd < r8 ? xcd * (q8 + 1) : r8 * (q8 + 1) + (xcd - r8) * q8) + loc;
  int bx = id / ny, by = id - bx * ny;
  int n0 = bx * 256, m0 = by * 256;

  int t = threadIdx.x;
  int wid = t >> 6, lane = t & 63;
  int wr = wid >> 2, wc = wid & 3, bh = wc >> 1;
  int l15 = lane & 15, l4 = lane >> 4;

  char* AS0 = lds;              char* AS1 = lds + 16384;
  char* AS2 = lds + 32768;      char* AS3 = lds + 49152;
  char* BS0 = lds + 65536;      char* BS1 = lds + 81920;
  char* BS2 = lds + 98304;      char* BS3 = lds + 114688;

  const char* ASe = lds + wr * 16384;            // even-tile A slot for this wave
  const char* ASo = ASe + 32768;                 // odd-tile
  const char* BSe = lds + 65536 + bh * 16384;
  const char* BSo = BSe + 32768;

  int brow = (wc & 1) * 64;    // wave-local base row inside B slot

  f32x4 acc[8][4] = {};
  short8 a[8];
  short8 b0, b1;

  int NT = K >> 6;       // 64-wide K-tiles
  int NI = NT >> 1;      // 8-phase iterations

  // ---- prologue: tile0 (4 half-tiles) + A(1,h0) ----
  stage_half(A,  K, m0,       0,  AS0, t);
  stage_half(A,  K, m0 + 128, 0,  AS1, t);
  stage_half(Bt, K, n0,       0,  BS0, t);
  stage_half(Bt, K, n0 + 128, 0,  BS1, t);
  stage_half(A,  K, m0,       64, AS2, t);
  asm volatile("s_waitcnt vmcnt(2)" ::: "memory");
  __builtin_amdgcn_s_barrier();
  __builtin_amdgcn_sched_barrier(0);

  for (int I = 0; I < NI; ++I) {
    int t0k = I * 128;
    int t1k = t0k + 64;
    bool notlast = (I + 1 < NI);

    // ---- phase 0: quad(kk=0, nh=0) of even tile ----
    #pragma unroll
    for (int mi = 0; mi < 8; ++mi) a[mi] = read_frag<0>(ASe, mi * 16 + l15, l4);
    b0 = read_frag<0>(BSe, brow + l15, l4);
    b1 = read_frag<0>(BSe, brow + 16 + l15, l4);
    stage_half(A, K, m0 + 128, t1k, AS3, t);
    __builtin_amdgcn_s_barrier();
    mfma_quad<0>(acc, a, b0, b1);
    __builtin_amdgcn_s_barrier();

    // ---- phase 1: quad(kk=0, nh=1) ----
    b0 = read_frag<0>(BSe, brow + 32 + l15, l4);
    b1 = read_frag<0>(BSe, brow + 48 + l15, l4);
    stage_half(Bt, K, n0, t1k, BS2, t);
    __builtin_amdgcn_s_barrier();
    mfma_quad<1>(acc, a, b0, b1);
    __builtin_amdgcn_s_barrier();

    // ---- phase 2: quad(kk=1, nh=0) ----
    #pragma unroll
    for (int mi = 0; mi < 8; ++mi) a[mi] = read_frag<1>(ASe, mi * 16 + l15, l4);
    b0 = read_frag<1>(BSe, brow + l15, l4);
    b1 = read_frag<1>(BSe, brow + 16 + l15, l4);
    stage_half(Bt, K, n0 + 128, t1k, BS3, t);
    __builtin_amdgcn_s_barrier();
    mfma_quad<0>(acc, a, b0, b1);
    __builtin_amdgcn_s_barrier();

    // ---- phase 3: quad(kk=1, nh=1) ----
    b0 = read_frag<1>(BSe, brow + 32 + l15, l4);
    b1 = read_frag<1>(BSe, brow + 48 + l15, l4);
    if (notlast) stage_half(A, K, m0, t0k + 128, AS0, t);
    if (notlast) { asm volatile("s_waitcnt vmcnt(2)" ::: "memory"); }
    else         { asm volatile("s_waitcnt vmcnt(0)" ::: "memory"); }
    __builtin_amdgcn_s_barrier();
    __builtin_amdgcn_sched_barrier(0);
    mfma_quad<1>(acc, a, b0, b1);
    __builtin_amdgcn_s_barrier();

    // ---- phase 4: quad(kk=0, nh=0) of odd tile ----
    #pragma unroll
    for (int mi = 0; mi < 8; ++mi) a[mi] = read_frag<0>(ASo, mi * 16 + l15, l4);
    b0 = read_frag<0>(BSo, brow + l15, l4);
    b1 = read_frag<0>(BSo, brow + 16 + l15, l4);
    if (notlast) stage_half(A, K, m0 + 128, t0k + 128, AS1, t);
    __builtin_amdgcn_s_barrier();
    mfma_quad<0>(acc, a, b0, b1);
    __builtin_amdgcn_s_barrier();

    // ---- phase 5: quad(kk=0, nh=1) ----
    b0 = read_frag<0>(BSo, brow + 32 + l15, l4);
    b1 = read_frag<0>(BSo, brow + 48 + l15, l4);
    if (notlast) stage_half(Bt, K, n0, t0k + 128, BS0, t);
    __builtin_amdgcn_s_barrier();
    mfma_quad<1>(acc, a, b0, b1);
    __builtin_amdgcn_s_barrier();

    // ---- phase 6: quad(kk=1, nh=0) ----
    #pragma unroll
    for (int mi = 0; mi < 8; ++mi) a[mi] = read_frag<1>(ASo, mi * 16 + l15, l4);
    b0 = read_frag<1>(BSo, brow + l15, l4);
    b1 = read_frag<1>(BSo, brow + 16 + l15, l4);
    if (notlast) stage_half(Bt, K, n0 + 128, t0k + 128, BS1, t);
    __builtin_amdgcn_s_barrier();
    mfma_quad<0>(acc, a, b0, b1);
    __builtin_amdgcn_s_barrier();

    // ---- phase 7: quad(kk=1, nh=1) ----
    b0 = read_frag<1>(BSo, brow + 32 + l15, l4);
    b1 = read_frag<1>(BSo, brow + 48 + l15, l4);
    if (notlast) {
      stage_half(A, K, m0, t0k + 192, AS2, t);
      asm volatile("s_waitcnt vmcnt(2)" ::: "memory");
    }
    __builtin_amdgcn_s_barrier();
    __builtin_amdgcn_sched_barrier(0);
    mfma_quad<1>(acc, a, b0, b1);
    __builtin_amdgcn_s_barrier();
  }

  // ---- epilogue ----
  #pragma unroll
  for (int mi = 0; mi < 8; ++mi)
    #pragma unroll
    for (int ni = 0; ni < 4; ++ni) {
      int col = n0 + wc * 64 + ni * 16 + l15;
      #pragma unroll
      for (int rr = 0; rr < 4; ++rr) {
        int row = m0 + wr * 128 + mi * 16 + l4 * 4 + rr;
        float v = acc[mi][ni][rr];
        if (MODE == 0) {
          ((bf16u*)C)[(size_t)row * N + col] = f2bf(v);
        } else if (MODE == 1) {
          float* p = (float*)C + (size_t)row * N + col;
          *p += v;
        } else {
          ((float*)C)[(size_t)row * N + col] = v;
        }
      }
    }
}

// ---------------- sliding-window flash attention (unchanged) ----------------
__global__ __launch_bounds__(256) void attn_kernel(const bf16u* __restrict__ q_bf,
                                                   const bf16u* __restrict__ k_bf,
                                                   const bf16u* __restrict__ v_bf,
                                                   bf16u* __restrict__ attn_out) {
  int h = blockIdx.y;
  int q0 = blockIdx.x * 64;
  int kvh = h >> 2;
  const bf16u* Kp = k_bf + (size_t)kvh * SEQ * DKH;
  const bf16u* Vp = v_bf + (size_t)kvh * SEQ * DKH;

  __shared__ __align__(16) char  Klds[32 * 128 * 2];
  __shared__ __align__(16) bf16u Vlds[128][40];
  __shared__ __align__(16) bf16u Plds[4][16][40];

  int t = threadIdx.x, wave = t >> 6, lane = t & 63;
  int l15 = lane & 15, l4 = lane >> 4;
  int qrow0 = q0 + wave * 16;

  short8 qf[4];
  #pragma unroll
  for (int ks = 0; ks < 4; ++ks)
    qf[ks] = *(const short8*)(q_bf + ((size_t)h * SEQ + qrow0 + l15) * DKH + ks * 32 + l4 * 8);

  f32x4 o[8] = {};
  float m[4], lsum[4];
  #pragma unroll
  for (int r = 0; r < 4; ++r) { m[r] = -INFINITY; lsum[r] = 0.0f; }

  int jstart = q0 >= (WIN - 1) ? ((q0 - (WIN - 1)) & ~31) : 0;

  for (int j0 = jstart; j0 < q0 + 64; j0 += 32) {
    __syncthreads();
    #pragma unroll
    for (int i = 0; i < 2; ++i) {
      int c = t + i * 256;
      int key = c >> 4, cc = c & 15;
      int off = key * 256 + cc * 16; off ^= (key & 7) << 4;
      *(short8*)(Klds + off) = *(const short8*)(Kp + (size_t)(j0 + key) * DKH + cc * 8);
    }
    {
      int key = t >> 3, d0 = (t & 7) * 16;
      const bf16u* src = Vp + (size_t)(j0 + key) * DKH + d0;
      #pragma unroll
      for (int i = 0; i < 16; ++i) Vlds[d0 + i][key] = src[i];
    }
    __syncthreads();

    f32x4 sacc[2] = {};
    #pragma unroll
    for (int nt = 0; nt < 2; ++nt) {
      int key = nt * 16 + l15;
      #pragma unroll
      for (int ks = 0; ks < 4; ++ks) {
        int off = key * 256 + ks * 64 + l4 * 16; off ^= (key & 7) << 4;
        short8 kf = *(short8*)(Klds + off);
        sacc[nt] = __builtin_amdgcn_mfma_f32_16x16x32_bf16(qf[ks], kf, sacc[nt], 0, 0, 0);
      }
    }

    float sv[2][4];
    #pragma unroll
    for (int nt = 0; nt < 2; ++nt) {
      int jk = j0 + nt * 16 + l15;
      #pragma unroll
      for (int r = 0; r < 4; ++r) {
        int iq = qrow0 + l4 * 4 + r;
        float s = sacc[nt][r] * 0.08838834764831845f;
        bool valid = (jk <= iq) && (iq - jk < WIN);
        sv[nt][r] = valid ? s : -1e9f;
      }
    }

    float p[2][4];
    #pragma unroll
    for (int r = 0; r < 4; ++r) {
      float mx = fmaxf(sv[0][r], sv[1][r]);
      #pragma unroll
      for (int off = 1; off < 16; off <<= 1) mx = fmaxf(mx, __shfl_xor(mx, off));
      float mn = fmaxf(m[r], mx);
      float alpha = __expf(m[r] - mn);
      p[0][r] = __expf(sv[0][r] - mn);
      p[1][r] = __expf(sv[1][r] - mn);
      float ps = p[0][r] + p[1][r];
      #pragma unroll
      for (int off = 1; off < 16; off <<= 1) ps += __shfl_xor(ps, off);
      lsum[r] = lsum[r] * alpha + ps;
      m[r] = mn;
      #pragma unroll
      for (int d = 0; d < 8; ++d) o[d][r] *= alpha;
    }

    #pragma unroll
    for (int nt = 0; nt < 2; ++nt)
      #pragma unroll
      for (int r = 0; r < 4; ++r)
        Plds[wave][l4 * 4 + r][nt * 16 + l15] = f2bf(p[nt][r]);

    short8 pf = *(short8*)(&Plds[wave][l15][l4 * 8]);
    #pragma unroll
    for (int d = 0; d < 8; ++d) {
      short8 vf = *(short8*)(&Vlds[d * 16 + l15][l4 * 8]);
      o[d] = __builtin_amdgcn_mfma_f32_16x16x32_bf16(pf, vf, o[d], 0, 0, 0);
    }
  }

  #pragma unroll
  for (int d = 0; d < 8; ++d)
    #pragma unroll
    for (int r = 0; r < 4; ++r) {
      int row = qrow0 + l4 * 4 + r;
      attn_out[(size_t)row * (NHEAD * DKH) + h * DKH + d * 16 + l15] = f2bf(o[d][r] / lsum[r]);
    }
}

// ---------------- host ----------------
extern "C" void kernel_launch(void* const* d_in, const int* in_sizes, int n_in,
                              void* d_out, int out_size, void* d_ws, size_t ws_size,
                              hipStream_t stream) {
  const int*   tokens  = (const int*)d_in[0];
  const float* table   = (const float*)d_in[1];
  const float* wq      = (const float*)d_in[2];
  const float* wk      = (const float*)d_in[3];
  const float* wv      = (const float*)d_in[4];
  const float* wo      = (const float*)d_in[5];
  const float* w_up    = (const float*)d_in[6];
  const float* w_down  = (const float*)d_in[7];
  const float* w_vocab = (const float*)d_in[8];
  float* out = (float*)d_out;

  char* base = (char*)d_ws;
  size_t o = 0;
  auto alloc = [&](size_t bytes) { size_t r = o; o += (bytes + 255) & ~(size_t)255; return r; };
  size_t o_x     = alloc((size_t)SEQ * EMB * 4);
  size_t o_nbf   = alloc((size_t)SEQ * EMB * 2);
  size_t o_qkvw  = alloc((size_t)QKV_N * EMB * 2);
  size_t o_wot   = alloc((size_t)EMB * EMB * 2);
  size_t o_wupt  = alloc((size_t)2 * HIDN * EMB * 2);
  size_t o_wdnt  = alloc((size_t)EMB * HIDN * 2);
  size_t o_qkvf  = alloc((size_t)SEQ * QKV_N * 4);
  size_t o_qbf   = alloc((size_t)NHEAD * SEQ * DKH * 2);
  size_t o_kbf   = alloc((size_t)NKV * SEQ * DKH * 2);
  size_t o_vbf   = alloc((size_t)NKV * SEQ * DKH * 2);
  size_t o_attn  = alloc((size_t)SEQ * EMB * 2);
  size_t o_guf   = alloc((size_t)SEQ * 2 * HIDN * 4);
  size_t o_hbf   = alloc((size_t)SEQ * HIDN * 2);
  size_t o_wvoct = o_guf;  // alias: vocab weight reuses gu region (dead by then)

  float* x      = (float*)(base + o_x);
  bf16u* n_bf   = (bf16u*)(base + o_nbf);
  bf16u* qkvw_t = (bf16u*)(base + o_qkvw);
  bf16u* wo_t   = (bf16u*)(base + o_wot);
  bf16u* wup_t  = (bf16u*)(base + o_wupt);
  bf16u* wdn_t  = (bf16u*)(base + o_wdnt);
  float* qkv_f  = (float*)(base + o_qkvf);
  bf16u* q_bf   = (bf16u*)(base + o_qbf);
  bf16u* k_bf   = (bf16u*)(base + o_kbf);
  bf16u* v_bf   = (bf16u*)(base + o_vbf);
  bf16u* attn_b = (bf16u*)(base + o_attn);
  float* gu_f   = (float*)(base + o_guf);
  bf16u* h_bf   = (bf16u*)(base + o_hbf);
  bf16u* wvoc_t = (bf16u*)(base + o_wvoct);

  embed_kernel<<<SEQ, 256, 0, stream>>>(tokens, table, x);

  for (int l = 0; l < NLAY; ++l) {
    transp_kernel<<<dim3(EMB / 32, EMB / 32), 256, 0, stream>>>(
        wq + (size_t)l * EMB * EMB, qkvw_t, EMB, EMB);
    transp_kernel<<<dim3(512 / 32, EMB / 32), 256, 0, stream>>>(
        wk + (size_t)l * EMB * 512, qkvw_t + (size_t)2048 * EMB, EMB, 512);
    transp_kernel<<<dim3(512 / 32, EMB / 32), 256, 0, stream>>>(
        wv + (size_t)l * EMB * 512, qkvw_t + (size_t)2560 * EMB, EMB, 512);
    transp_kernel<<<dim3(EMB / 32, EMB / 32), 256, 0, stream>>>(
        wo + (size_t)l * EMB * EMB, wo_t, EMB, EMB);
    transp_kernel<<<dim3(2 * HIDN / 32, EMB / 32), 256, 0, stream>>>(
        w_up + (size_t)l * EMB * 2 * HIDN, wup_t, EMB, 2 * HIDN);
    transp_kernel<<<dim3(EMB / 32, HIDN / 32), 256, 0, stream>>>(
        w_down + (size_t)l * HIDN * EMB, wdn_t, HIDN, EMB);

    rmsnorm_kernel<<<SEQ, 256, 0, stream>>>(x, n_bf);
    gemm256_kernel<2><<<dim3(QKV_N / 256, SEQ / 256), 512, 0, stream>>>(
        n_bf, qkvw_t, qkv_f, SEQ, QKV_N, EMB);

    rope_kernel<<<NHEAD * SEQ * 64 / 256, 256, 0, stream>>>(qkv_f, q_bf, 0);
    rope_kernel<<<NKV * SEQ * 64 / 256, 256, 0, stream>>>(qkv_f, k_bf, 2048);
    vconv_kernel<<<NKV * SEQ * 128 / 256, 256, 0, stream>>>(qkv_f, v_bf);

    attn_kernel<<<dim3(SEQ / 64, NHEAD), 256, 0, stream>>>(q_bf, k_bf, v_bf, attn_b);

    gemm256_kernel<1><<<dim3(EMB / 256, SEQ / 256), 512, 0, stream>>>(
        attn_b, wo_t, x, SEQ, EMB, EMB);

    rmsnorm_kernel<<<SEQ, 256, 0, stream>>>(x, n_bf);
    gemm256_kernel<2><<<dim3(2 * HIDN / 256, SEQ / 256), 512, 0, stream>>>(
        n_bf, wup_t, gu_f, SEQ, 2 * HIDN, EMB);
    swiglu_kernel<<<SEQ * HIDN / 256, 256, 0, stream>>>(gu_f, h_bf);
    gemm256_kernel<1><<<dim3(EMB / 256, SEQ / 256), 512, 0, stream>>>(
        h_bf, wdn_t, x, SEQ, EMB, HIDN);
  }

  transp_kernel<<<dim3(NVOC / 32, EMB / 32), 256, 0, stream>>>(w_vocab, wvoc_t, EMB, NVOC);
  rmsnorm_kernel<<<SEQ, 256, 0, stream>>>(x, n_bf);
  gemm256_kernel<2><<<dim3(NVOC / 256, SEQ / 256), 512, 0, stream>>>(
      n_bf, wvoc_t, out, SEQ, NVOC, EMB);
}

// Round 4
// 2688.248 us; speedup vs baseline: 1.3151x; 1.3151x over previous
//
#include <hip/hip_runtime.h>
#include <cstdint>

typedef unsigned short bf16u;
typedef __attribute__((ext_vector_type(8))) short short8;
typedef __attribute__((ext_vector_type(4))) float f32x4;

#define SEQ   2048
#define EMB   2048
#define NHEAD 16
#define NKV   4
#define DKH   128
#define HIDN  8192
#define NVOC  32000
#define NLAY  4
#define WIN   1024
#define QKV_N 3072

__device__ __forceinline__ bf16u f2bf(float f) {
  union { float f; uint32_t u; } v; v.f = f;
  uint32_t r = v.u + 0x7FFFu + ((v.u >> 16) & 1u);
  return (bf16u)(r >> 16);
}

__device__ __forceinline__ void gl2lds16(const void* g, void* l) {
  __builtin_amdgcn_global_load_lds(
      (const __attribute__((address_space(1))) void*)g,
      (__attribute__((address_space(3))) void*)l, 16, 0, 0);
}

// ---------------- embedding ----------------
__global__ __launch_bounds__(256) void embed_kernel(const int* __restrict__ tokens,
                                                    const float* __restrict__ table,
                                                    float* __restrict__ x) {
  int s = blockIdx.x;
  int tok = tokens[s];
  int i0 = threadIdx.x * 8;
  float4 a = {0,0,0,0}, b = {0,0,0,0};
  if (tok != 0) {
    const float* src = table + (size_t)tok * EMB;
    a = *(const float4*)(src + i0);
    b = *(const float4*)(src + i0 + 4);
  }
  *(float4*)(x + (size_t)s * EMB + i0) = a;
  *(float4*)(x + (size_t)s * EMB + i0 + 4) = b;
}

// ---------------- rmsnorm ----------------
__global__ __launch_bounds__(256) void rmsnorm_kernel(const float* __restrict__ x,
                                                      bf16u* __restrict__ out) {
  int s = blockIdx.x;
  const float* row = x + (size_t)s * EMB;
  int i0 = threadIdx.x * 8;
  float4 a = *(const float4*)(row + i0);
  float4 b = *(const float4*)(row + i0 + 4);
  float ss = a.x*a.x + a.y*a.y + a.z*a.z + a.w*a.w
           + b.x*b.x + b.y*b.y + b.z*b.z + b.w*b.w;
  #pragma unroll
  for (int off = 1; off < 64; off <<= 1) ss += __shfl_xor(ss, off);
  __shared__ float red[4];
  if ((threadIdx.x & 63) == 0) red[threadIdx.x >> 6] = ss;
  __syncthreads();
  float scale = rsqrtf((red[0] + red[1] + red[2] + red[3]) * (1.0f / EMB) + 1e-5f);
  float v[8] = {a.x, a.y, a.z, a.w, b.x, b.y, b.z, b.w};
  short8 o;
  #pragma unroll
  for (int j = 0; j < 8; ++j) o[j] = (short)f2bf(v[j] * scale);
  *(short8*)(out + (size_t)s * EMB + i0) = o;
}

// ---------------- transpose + convert ----------------
__global__ __launch_bounds__(256) void transp_kernel(const float* __restrict__ in,
                                                     bf16u* __restrict__ out,
                                                     int R, int C) {
  __shared__ float tile[32][33];
  int c0 = blockIdx.x * 32, r0 = blockIdx.y * 32;
  int tx = threadIdx.x & 31, ty = threadIdx.x >> 5;
  #pragma unroll
  for (int i = 0; i < 4; ++i)
    tile[ty + i * 8][tx] = in[(size_t)(r0 + ty + i * 8) * C + c0 + tx];
  __syncthreads();
  #pragma unroll
  for (int i = 0; i < 4; ++i)
    out[(size_t)(c0 + ty + i * 8) * R + r0 + tx] = f2bf(tile[tx][ty + i * 8]);
}

// ---------------- RoPE ----------------
__global__ __launch_bounds__(256) void rope_kernel(const float* __restrict__ qkv,
                                                   bf16u* __restrict__ out, int col0) {
  int idx = blockIdx.x * 256 + threadIdx.x;
  int d = idx & 63;
  int s = (idx >> 6) & (SEQ - 1);
  int h = idx >> 17;
  const float* row = qkv + (size_t)s * QKV_N + col0 + h * DKH;
  float ang = (float)s * __powf(10000.0f, -(float)d * (1.0f / 64.0f));
  float si, c;
  sincosf(ang, &si, &c);
  float f0 = row[d], f1 = row[d + 64];
  bf16u* orow = out + ((size_t)h * SEQ + s) * DKH;
  orow[d]      = f2bf(c * f0 - si * f1);
  orow[d + 64] = f2bf(c * f1 + si * f0);
}

__global__ __launch_bounds__(256) void vconv_kernel(const float* __restrict__ qkv,
                                                    bf16u* __restrict__ vout) {
  int idx = blockIdx.x * 256 + threadIdx.x;
  int d = idx & 127;
  int kv = (idx >> 7) & 3;
  int s = idx >> 9;
  vout[((size_t)kv * SEQ + s) * DKH + d] = f2bf(qkv[(size_t)s * QKV_N + 2560 + kv * DKH + d]);
}

// ---------------- swiglu ----------------
__global__ __launch_bounds__(256) void swiglu_kernel(const float* __restrict__ gu,
                                                     bf16u* __restrict__ h) {
  size_t idx = (size_t)blockIdx.x * 256 + threadIdx.x;
  int s = (int)(idx >> 13);
  int j = (int)(idx & 8191);
  float g = gu[(size_t)s * 16384 + j];
  float u = gu[(size_t)s * 16384 + 8192 + j];
  float sil = g / (1.0f + __expf(-g));
  h[idx] = f2bf(u * sil);
}

// ---------------- split-K reduce: x += p0+p1+p2+p3 ----------------
__global__ __launch_bounds__(256) void reduce4_kernel(float* __restrict__ x,
                                                      const float* __restrict__ p) {
  size_t i = ((size_t)blockIdx.x * 256 + threadIdx.x) * 4;
  const size_t MN = (size_t)SEQ * EMB;
  float4 a = *(const float4*)(x + i);
  float4 b0 = *(const float4*)(p + i);
  float4 b1 = *(const float4*)(p + i + MN);
  float4 b2 = *(const float4*)(p + i + 2 * MN);
  float4 b3 = *(const float4*)(p + i + 3 * MN);
  a.x += b0.x + b1.x + b2.x + b3.x;
  a.y += b0.y + b1.y + b2.y + b3.y;
  a.z += b0.z + b1.z + b2.z + b3.z;
  a.w += b0.w + b1.w + b2.w + b3.w;
  *(float4*)(x + i) = a;
}

// ================= 128x128 2-phase GEMM (full-GPU shapes, small N) =================
// MODE 0: write bf16; MODE 1: f32 C += ; MODE 2: write f32
template <int MODE>
__global__ __launch_bounds__(256) void gemm_kernel(const bf16u* __restrict__ A,
                                                   const bf16u* __restrict__ Bt,
                                                   void* __restrict__ C,
                                                   int M, int N, int K) {
  __shared__ __align__(16) char lds[2][2][8192];

  int nx = gridDim.x, ny = gridDim.y;
  int nwg = nx * ny;
  int orig = blockIdx.y * nx + blockIdx.x;
  int q = nwg >> 3, r = nwg & 7;
  int xcd = orig & 7, loc = orig >> 3;
  int id = (xcd < r ? xcd * (q + 1) : r * (q + 1) + (xcd - r) * q) + loc;
  int bx = id / ny, by = id - bx * ny;
  int n0 = bx * 128, m0 = by * 128;

  int t = threadIdx.x;
  int w = t >> 6, l = t & 63;
  int wm = (w >> 1) * 64, wn = (w & 1) * 64;
  int l15 = l & 15, l4 = l >> 4;

  int srow = w * 16 + (l >> 2);
  int scol = (l & 3) * 8;

  f32x4 acc[4][4] = {};

  auto stage = [&](int buf, int k0) {
    #pragma unroll
    for (int i = 0; i < 2; ++i) {
      gl2lds16(A  + (size_t)(m0 + i * 64 + srow) * K + k0 + scol,
               &lds[buf][0][i * 4096 + w * 1024]);
      gl2lds16(Bt + (size_t)(n0 + i * 64 + srow) * K + k0 + scol,
               &lds[buf][1][i * 4096 + w * 1024]);
    }
  };

  auto compute = [&](int buf) {
    short8 af[4], bfr[4];
    #pragma unroll
    for (int i = 0; i < 4; ++i) {
      af[i]  = *(const short8*)(&lds[buf][0][((wm + i * 16 + l15) * 32 + l4 * 8) * 2]);
      bfr[i] = *(const short8*)(&lds[buf][1][((wn + i * 16 + l15) * 32 + l4 * 8) * 2]);
    }
    #pragma unroll
    for (int i = 0; i < 4; ++i)
      #pragma unroll
      for (int j = 0; j < 4; ++j)
        acc[i][j] = __builtin_amdgcn_mfma_f32_16x16x32_bf16(af[i], bfr[j], acc[i][j], 0, 0, 0);
  };

  int nt = K >> 5;
  int cur = 0;
  stage(0, 0);
  __syncthreads();
  for (int tt = 0; tt < nt; ++tt) {
    if (tt + 1 < nt) stage(cur ^ 1, (tt + 1) * 32);
    compute(cur);
    __syncthreads();
    cur ^= 1;
  }

  #pragma unroll
  for (int i = 0; i < 4; ++i)
    #pragma unroll
    for (int j = 0; j < 4; ++j) {
      int col = n0 + wn + j * 16 + l15;
      #pragma unroll
      for (int rr = 0; rr < 4; ++rr) {
        int row = m0 + wm + i * 16 + l4 * 4 + rr;
        float v = acc[i][j][rr];
        if (MODE == 0) {
          ((bf16u*)C)[(size_t)row * N + col] = f2bf(v);
        } else if (MODE == 1) {
          float* p = (float*)C + (size_t)row * N + col;
          *p += v;
        } else {
          ((float*)C)[(size_t)row * N + col] = v;
        }
      }
    }
}

// ================= 256x256 8-phase GEMM (T1+T2+T3+T4+T5) =================
// ldk = row stride of A/Bt; K = K-extent per z-slice; blockIdx.z = split index
// (k-offset z*K, C slab offset z*M*N for MODE 2).
__device__ __forceinline__ void stage_half(const bf16u* __restrict__ p, int ld,
                                           int row0, int k0, char* slotBase, int t) {
  int r  = t >> 3, c8 = t & 7;
  int cs = (c8 ^ (r & 7)) << 3;
  gl2lds16(p + (size_t)(row0 + r) * ld + k0 + cs, slotBase + t * 16);
  gl2lds16(p + (size_t)(row0 + 64 + r) * ld + k0 + cs, slotBase + 8192 + t * 16);
}

template<int KK>
__device__ __forceinline__ short8 read_frag(const char* slot, int row, int l4) {
  int kc = KK * 4 + l4;
  return *(const short8*)(slot + row * 128 + ((kc ^ (row & 7)) << 4));
}

template<int NH>
__device__ __forceinline__ void mfma_quad(f32x4 (&acc)[8][4], const short8 (&a)[8],
                                          short8 b0, short8 b1) {
  __builtin_amdgcn_s_setprio(1);
  #pragma unroll
  for (int mi = 0; mi < 8; ++mi) {
    acc[mi][NH * 2]     = __builtin_amdgcn_mfma_f32_16x16x32_bf16(a[mi], b0, acc[mi][NH * 2], 0, 0, 0);
    acc[mi][NH * 2 + 1] = __builtin_amdgcn_mfma_f32_16x16x32_bf16(a[mi], b1, acc[mi][NH * 2 + 1], 0, 0, 0);
  }
  __builtin_amdgcn_s_setprio(0);
}

template <int MODE>
__global__ __launch_bounds__(512) void gemm256_kernel(const bf16u* __restrict__ A,
                                                      const bf16u* __restrict__ Bt,
                                                      void* __restrict__ C,
                                                      int M, int N, int K, int ldk) {
  __shared__ __align__(16) char lds[131072];

  int koff = blockIdx.z * K;
  A  += koff;
  Bt += koff;
  float* Cz = (float*)C + (size_t)blockIdx.z * M * N;   // MODE 2 split-K slab

  int nx = gridDim.x, ny = gridDim.y;
  int nwg = nx * ny;
  int orig = blockIdx.y * nx + blockIdx.x;
  int q8 = nwg >> 3, r8 = nwg & 7;
  int xcd = orig & 7, loc = orig >> 3;
  int id = (xcd < r8 ? xcd * (q8 + 1) : r8 * (q8 + 1) + (xcd - r8) * q8) + loc;
  int bx = id / ny, by = id - bx * ny;
  int n0 = bx * 256, m0 = by * 256;

  int t = threadIdx.x;
  int wid = t >> 6, lane = t & 63;
  int wr = wid >> 2, wc = wid & 3, bh = wc >> 1;
  int l15 = lane & 15, l4 = lane >> 4;

  char* AS0 = lds;              char* AS1 = lds + 16384;
  char* AS2 = lds + 32768;      char* AS3 = lds + 49152;
  char* BS0 = lds + 65536;      char* BS1 = lds + 81920;
  char* BS2 = lds + 98304;      char* BS3 = lds + 114688;

  const char* ASe = lds + wr * 16384;
  const char* ASo = ASe + 32768;
  const char* BSe = lds + 65536 + bh * 16384;
  const char* BSo = BSe + 32768;

  int brow = (wc & 1) * 64;

  f32x4 acc[8][4] = {};
  short8 a[8];
  short8 b0, b1;

  int NT = K >> 6;
  int NI = NT >> 1;

  stage_half(A,  ldk, m0,       0,  AS0, t);
  stage_half(A,  ldk, m0 + 128, 0,  AS1, t);
  stage_half(Bt, ldk, n0,       0,  BS0, t);
  stage_half(Bt, ldk, n0 + 128, 0,  BS1, t);
  stage_half(A,  ldk, m0,       64, AS2, t);
  asm volatile("s_waitcnt vmcnt(2)" ::: "memory");
  __builtin_amdgcn_s_barrier();
  __builtin_amdgcn_sched_barrier(0);

  for (int I = 0; I < NI; ++I) {
    int t0k = I * 128;
    int t1k = t0k + 64;
    bool notlast = (I + 1 < NI);

    #pragma unroll
    for (int mi = 0; mi < 8; ++mi) a[mi] = read_frag<0>(ASe, mi * 16 + l15, l4);
    b0 = read_frag<0>(BSe, brow + l15, l4);
    b1 = read_frag<0>(BSe, brow + 16 + l15, l4);
    stage_half(A, ldk, m0 + 128, t1k, AS3, t);
    __builtin_amdgcn_s_barrier();
    mfma_quad<0>(acc, a, b0, b1);
    __builtin_amdgcn_s_barrier();

    b0 = read_frag<0>(BSe, brow + 32 + l15, l4);
    b1 = read_frag<0>(BSe, brow + 48 + l15, l4);
    stage_half(Bt, ldk, n0, t1k, BS2, t);
    __builtin_amdgcn_s_barrier();
    mfma_quad<1>(acc, a, b0, b1);
    __builtin_amdgcn_s_barrier();

    #pragma unroll
    for (int mi = 0; mi < 8; ++mi) a[mi] = read_frag<1>(ASe, mi * 16 + l15, l4);
    b0 = read_frag<1>(BSe, brow + l15, l4);
    b1 = read_frag<1>(BSe, brow + 16 + l15, l4);
    stage_half(Bt, ldk, n0 + 128, t1k, BS3, t);
    __builtin_amdgcn_s_barrier();
    mfma_quad<0>(acc, a, b0, b1);
    __builtin_amdgcn_s_barrier();

    b0 = read_frag<1>(BSe, brow + 32 + l15, l4);
    b1 = read_frag<1>(BSe, brow + 48 + l15, l4);
    if (notlast) stage_half(A, ldk, m0, t0k + 128, AS0, t);
    if (notlast) { asm volatile("s_waitcnt vmcnt(2)" ::: "memory"); }
    else         { asm volatile("s_waitcnt vmcnt(0)" ::: "memory"); }
    __builtin_amdgcn_s_barrier();
    __builtin_amdgcn_sched_barrier(0);
    mfma_quad<1>(acc, a, b0, b1);
    __builtin_amdgcn_s_barrier();

    #pragma unroll
    for (int mi = 0; mi < 8; ++mi) a[mi] = read_frag<0>(ASo, mi * 16 + l15, l4);
    b0 = read_frag<0>(BSo, brow + l15, l4);
    b1 = read_frag<0>(BSo, brow + 16 + l15, l4);
    if (notlast) stage_half(A, ldk, m0 + 128, t0k + 128, AS1, t);
    __builtin_amdgcn_s_barrier();
    mfma_quad<0>(acc, a, b0, b1);
    __builtin_amdgcn_s_barrier();

    b0 = read_frag<0>(BSo, brow + 32 + l15, l4);
    b1 = read_frag<0>(BSo, brow + 48 + l15, l4);
    if (notlast) stage_half(Bt, ldk, n0, t0k + 128, BS0, t);
    __builtin_amdgcn_s_barrier();
    mfma_quad<1>(acc, a, b0, b1);
    __builtin_amdgcn_s_barrier();

    #pragma unroll
    for (int mi = 0; mi < 8; ++mi) a[mi] = read_frag<1>(ASo, mi * 16 + l15, l4);
    b0 = read_frag<1>(BSo, brow + l15, l4);
    b1 = read_frag<1>(BSo, brow + 16 + l15, l4);
    if (notlast) stage_half(Bt, ldk, n0 + 128, t0k + 128, BS1, t);
    __builtin_amdgcn_s_barrier();
    mfma_quad<0>(acc, a, b0, b1);
    __builtin_amdgcn_s_barrier();

    b0 = read_frag<1>(BSo, brow + 32 + l15, l4);
    b1 = read_frag<1>(BSo, brow + 48 + l15, l4);
    if (notlast) {
      stage_half(A, ldk, m0, t0k + 192, AS2, t);
      asm volatile("s_waitcnt vmcnt(2)" ::: "memory");
    }
    __builtin_amdgcn_s_barrier();
    __builtin_amdgcn_sched_barrier(0);
    mfma_quad<1>(acc, a, b0, b1);
    __builtin_amdgcn_s_barrier();
  }

  #pragma unroll
  for (int mi = 0; mi < 8; ++mi)
    #pragma unroll
    for (int ni = 0; ni < 4; ++ni) {
      int col = n0 + wc * 64 + ni * 16 + l15;
      #pragma unroll
      for (int rr = 0; rr < 4; ++rr) {
        int row = m0 + wr * 128 + mi * 16 + l4 * 4 + rr;
        float v = acc[mi][ni][rr];
        if (MODE == 0) {
          ((bf16u*)C)[(size_t)row * N + col] = f2bf(v);
        } else if (MODE == 1) {
          float* p = (float*)C + (size_t)row * N + col;
          *p += v;
        } else {
          Cz[(size_t)row * N + col] = v;
        }
      }
    }
}

// ---------------- sliding-window flash attention ----------------
__global__ __launch_bounds__(256) void attn_kernel(const bf16u* __restrict__ q_bf,
                                                   const bf16u* __restrict__ k_bf,
                                                   const bf16u* __restrict__ v_bf,
                                                   bf16u* __restrict__ attn_out) {
  int h = blockIdx.y;
  int q0 = blockIdx.x * 64;
  int kvh = h >> 2;
  const bf16u* Kp = k_bf + (size_t)kvh * SEQ * DKH;
  const bf16u* Vp = v_bf + (size_t)kvh * SEQ * DKH;

  __shared__ __align__(16) char  Klds[32 * 128 * 2];
  __shared__ __align__(16) bf16u Vlds[128][40];
  __shared__ __align__(16) bf16u Plds[4][16][40];

  int t = threadIdx.x, wave = t >> 6, lane = t & 63;
  int l15 = lane & 15, l4 = lane >> 4;
  int qrow0 = q0 + wave * 16;

  short8 qf[4];
  #pragma unroll
  for (int ks = 0; ks < 4; ++ks)
    qf[ks] = *(const short8*)(q_bf + ((size_t)h * SEQ + qrow0 + l15) * DKH + ks * 32 + l4 * 8);

  f32x4 o[8] = {};
  float m[4], lsum[4];
  #pragma unroll
  for (int r = 0; r < 4; ++r) { m[r] = -INFINITY; lsum[r] = 0.0f; }

  int jstart = q0 >= (WIN - 1) ? ((q0 - (WIN - 1)) & ~31) : 0;

  for (int j0 = jstart; j0 < q0 + 64; j0 += 32) {
    __syncthreads();
    #pragma unroll
    for (int i = 0; i < 2; ++i) {
      int c = t + i * 256;
      int key = c >> 4, cc = c & 15;
      int off = key * 256 + cc * 16; off ^= (key & 7) << 4;
      *(short8*)(Klds + off) = *(const short8*)(Kp + (size_t)(j0 + key) * DKH + cc * 8);
    }
    {
      int key = t >> 3, d0 = (t & 7) * 16;
      const bf16u* src = Vp + (size_t)(j0 + key) * DKH + d0;
      #pragma unroll
      for (int i = 0; i < 16; ++i) Vlds[d0 + i][key] = src[i];
    }
    __syncthreads();

    f32x4 sacc[2] = {};
    #pragma unroll
    for (int nt = 0; nt < 2; ++nt) {
      int key = nt * 16 + l15;
      #pragma unroll
      for (int ks = 0; ks < 4; ++ks) {
        int off = key * 256 + ks * 64 + l4 * 16; off ^= (key & 7) << 4;
        short8 kf = *(short8*)(Klds + off);
        sacc[nt] = __builtin_amdgcn_mfma_f32_16x16x32_bf16(qf[ks], kf, sacc[nt], 0, 0, 0);
      }
    }

    float sv[2][4];
    #pragma unroll
    for (int nt = 0; nt < 2; ++nt) {
      int jk = j0 + nt * 16 + l15;
      #pragma unroll
      for (int r = 0; r < 4; ++r) {
        int iq = qrow0 + l4 * 4 + r;
        float s = sacc[nt][r] * 0.08838834764831845f;
        bool valid = (jk <= iq) && (iq - jk < WIN);
        sv[nt][r] = valid ? s : -1e9f;
      }
    }

    float p[2][4];
    #pragma unroll
    for (int r = 0; r < 4; ++r) {
      float mx = fmaxf(sv[0][r], sv[1][r]);
      #pragma unroll
      for (int off = 1; off < 16; off <<= 1) mx = fmaxf(mx, __shfl_xor(mx, off));
      float mn = fmaxf(m[r], mx);
      float alpha = __expf(m[r] - mn);
      p[0][r] = __expf(sv[0][r] - mn);
      p[1][r] = __expf(sv[1][r] - mn);
      float ps = p[0][r] + p[1][r];
      #pragma unroll
      for (int off = 1; off < 16; off <<= 1) ps += __shfl_xor(ps, off);
      lsum[r] = lsum[r] * alpha + ps;
      m[r] = mn;
      #pragma unroll
      for (int d = 0; d < 8; ++d) o[d][r] *= alpha;
    }

    #pragma unroll
    for (int nt = 0; nt < 2; ++nt)
      #pragma unroll
      for (int r = 0; r < 4; ++r)
        Plds[wave][l4 * 4 + r][nt * 16 + l15] = f2bf(p[nt][r]);

    short8 pf = *(short8*)(&Plds[wave][l15][l4 * 8]);
    #pragma unroll
    for (int d = 0; d < 8; ++d) {
      short8 vf = *(short8*)(&Vlds[d * 16 + l15][l4 * 8]);
      o[d] = __builtin_amdgcn_mfma_f32_16x16x32_bf16(pf, vf, o[d], 0, 0, 0);
    }
  }

  #pragma unroll
  for (int d = 0; d < 8; ++d)
    #pragma unroll
    for (int r = 0; r < 4; ++r) {
      int row = qrow0 + l4 * 4 + r;
      attn_out[(size_t)row * (NHEAD * DKH) + h * DKH + d * 16 + l15] = f2bf(o[d][r] / lsum[r]);
    }
}

// ---------------- host ----------------
extern "C" void kernel_launch(void* const* d_in, const int* in_sizes, int n_in,
                              void* d_out, int out_size, void* d_ws, size_t ws_size,
                              hipStream_t stream) {
  const int*   tokens  = (const int*)d_in[0];
  const float* table   = (const float*)d_in[1];
  const float* wq      = (const float*)d_in[2];
  const float* wk      = (const float*)d_in[3];
  const float* wv      = (const float*)d_in[4];
  const float* wo      = (const float*)d_in[5];
  const float* w_up    = (const float*)d_in[6];
  const float* w_down  = (const float*)d_in[7];
  const float* w_vocab = (const float*)d_in[8];
  float* out = (float*)d_out;

  char* base = (char*)d_ws;
  size_t o = 0;
  auto alloc = [&](size_t bytes) { size_t r = o; o += (bytes + 255) & ~(size_t)255; return r; };
  size_t o_x     = alloc((size_t)SEQ * EMB * 4);
  size_t o_nbf   = alloc((size_t)SEQ * EMB * 2);
  size_t o_qkvw  = alloc((size_t)QKV_N * EMB * 2);
  size_t o_wot   = alloc((size_t)EMB * EMB * 2);
  size_t o_wupt  = alloc((size_t)2 * HIDN * EMB * 2);
  size_t o_wdnt  = alloc((size_t)EMB * HIDN * 2);
  size_t o_qkvf  = alloc((size_t)SEQ * QKV_N * 4);
  size_t o_qbf   = alloc((size_t)NHEAD * SEQ * DKH * 2);
  size_t o_kbf   = alloc((size_t)NKV * SEQ * DKH * 2);
  size_t o_vbf   = alloc((size_t)NKV * SEQ * DKH * 2);
  size_t o_attn  = alloc((size_t)SEQ * EMB * 2);
  size_t o_guf   = alloc((size_t)SEQ * 2 * HIDN * 4);   // also: split-K partials (4x16MB), wvoc_t
  size_t o_hbf   = alloc((size_t)SEQ * HIDN * 2);
  size_t o_wvoct = o_guf;

  float* x      = (float*)(base + o_x);
  bf16u* n_bf   = (bf16u*)(base + o_nbf);
  bf16u* qkvw_t = (bf16u*)(base + o_qkvw);
  bf16u* wo_t   = (bf16u*)(base + o_wot);
  bf16u* wup_t  = (bf16u*)(base + o_wupt);
  bf16u* wdn_t  = (bf16u*)(base + o_wdnt);
  float* qkv_f  = (float*)(base + o_qkvf);
  bf16u* q_bf   = (bf16u*)(base + o_qbf);
  bf16u* k_bf   = (bf16u*)(base + o_kbf);
  bf16u* v_bf   = (bf16u*)(base + o_vbf);
  bf16u* attn_b = (bf16u*)(base + o_attn);
  float* gu_f   = (float*)(base + o_guf);
  float* part   = (float*)(base + o_guf);              // alias (gu dead during down-proj)
  bf16u* h_bf   = (bf16u*)(base + o_hbf);
  bf16u* wvoc_t = (bf16u*)(base + o_wvoct);

  embed_kernel<<<SEQ, 256, 0, stream>>>(tokens, table, x);

  for (int l = 0; l < NLAY; ++l) {
    transp_kernel<<<dim3(EMB / 32, EMB / 32), 256, 0, stream>>>(
        wq + (size_t)l * EMB * EMB, qkvw_t, EMB, EMB);
    transp_kernel<<<dim3(512 / 32, EMB / 32), 256, 0, stream>>>(
        wk + (size_t)l * EMB * 512, qkvw_t + (size_t)2048 * EMB, EMB, 512);
    transp_kernel<<<dim3(512 / 32, EMB / 32), 256, 0, stream>>>(
        wv + (size_t)l * EMB * 512, qkvw_t + (size_t)2560 * EMB, EMB, 512);
    transp_kernel<<<dim3(EMB / 32, EMB / 32), 256, 0, stream>>>(
        wo + (size_t)l * EMB * EMB, wo_t, EMB, EMB);
    transp_kernel<<<dim3(2 * HIDN / 32, EMB / 32), 256, 0, stream>>>(
        w_up + (size_t)l * EMB * 2 * HIDN, wup_t, EMB, 2 * HIDN);
    transp_kernel<<<dim3(EMB / 32, HIDN / 32), 256, 0, stream>>>(
        w_down + (size_t)l * HIDN * EMB, wdn_t, HIDN, EMB);

    rmsnorm_kernel<<<SEQ, 256, 0, stream>>>(x, n_bf);
    // qkv: N=3072 -> 128^2 tiles (384 WGs, full GPU)
    gemm_kernel<2><<<dim3(QKV_N / 128, SEQ / 128), 256, 0, stream>>>(
        n_bf, qkvw_t, qkv_f, SEQ, QKV_N, EMB);

    rope_kernel<<<NHEAD * SEQ * 64 / 256, 256, 0, stream>>>(qkv_f, q_bf, 0);
    rope_kernel<<<NKV * SEQ * 64 / 256, 256, 0, stream>>>(qkv_f, k_bf, 2048);
    vconv_kernel<<<NKV * SEQ * 128 / 256, 256, 0, stream>>>(qkv_f, v_bf);

    attn_kernel<<<dim3(SEQ / 64, NHEAD), 256, 0, stream>>>(q_bf, k_bf, v_bf, attn_b);

    // wo: N=2048 -> 128^2 tiles (256 WGs)
    gemm_kernel<1><<<dim3(EMB / 128, SEQ / 128), 256, 0, stream>>>(
        attn_b, wo_t, x, SEQ, EMB, EMB);

    rmsnorm_kernel<<<SEQ, 256, 0, stream>>>(x, n_bf);
    // up: N=16384 -> 256^2 8-phase (512 WGs)
    gemm256_kernel<2><<<dim3(2 * HIDN / 256, SEQ / 256), 512, 0, stream>>>(
        n_bf, wup_t, gu_f, SEQ, 2 * HIDN, EMB, EMB);
    swiglu_kernel<<<SEQ * HIDN / 256, 256, 0, stream>>>(gu_f, h_bf);
    // down: K=8192 -> 256^2 8-phase, 4-way split-K (256 WGs), then x += sum(partials)
    gemm256_kernel<2><<<dim3(EMB / 256, SEQ / 256, 4), 512, 0, stream>>>(
        h_bf, wdn_t, part, SEQ, EMB, 2048, HIDN);
    reduce4_kernel<<<SEQ * EMB / 1024, 256, 0, stream>>>(x, part);
  }

  transp_kernel<<<dim3(NVOC / 32, EMB / 32), 256, 0, stream>>>(w_vocab, wvoc_t, EMB, NVOC);
  rmsnorm_kernel<<<SEQ, 256, 0, stream>>>(x, n_bf);
  gemm256_kernel<2><<<dim3(NVOC / 256, SEQ / 256), 512, 0, stream>>>(
      n_bf, wvoc_t, out, SEQ, NVOC, EMB, EMB);
}

// Round 5
// 2504.735 us; speedup vs baseline: 1.4115x; 1.0733x over previous
//
#include <hip/hip_runtime.h>
#include <cstdint>

typedef unsigned short bf16u;
typedef __attribute__((ext_vector_type(8))) short short8;
typedef __attribute__((ext_vector_type(4))) float f32x4;

#define SEQ   2048
#define EMB   2048
#define NHEAD 16
#define NKV   4
#define DKH   128
#define HIDN  8192
#define NVOC  32000
#define NLAY  4
#define WIN   1024
#define QKV_N 3072

__device__ __forceinline__ bf16u f2bf(float f) {
  union { float f; uint32_t u; } v; v.f = f;
  uint32_t r = v.u + 0x7FFFu + ((v.u >> 16) & 1u);
  return (bf16u)(r >> 16);
}

__device__ __forceinline__ void gl2lds16(const void* g, void* l) {
  __builtin_amdgcn_global_load_lds(
      (const __attribute__((address_space(1))) void*)g,
      (__attribute__((address_space(3))) void*)l, 16, 0, 0);
}

// ---------------- embedding ----------------
__global__ __launch_bounds__(256) void embed_kernel(const int* __restrict__ tokens,
                                                    const float* __restrict__ table,
                                                    float* __restrict__ x) {
  int s = blockIdx.x;
  int tok = tokens[s];
  int i0 = threadIdx.x * 8;
  float4 a = {0,0,0,0}, b = {0,0,0,0};
  if (tok != 0) {
    const float* src = table + (size_t)tok * EMB;
    a = *(const float4*)(src + i0);
    b = *(const float4*)(src + i0 + 4);
  }
  *(float4*)(x + (size_t)s * EMB + i0) = a;
  *(float4*)(x + (size_t)s * EMB + i0 + 4) = b;
}

// ---------------- rmsnorm ----------------
__global__ __launch_bounds__(256) void rmsnorm_kernel(const float* __restrict__ x,
                                                      bf16u* __restrict__ out) {
  int s = blockIdx.x;
  const float* row = x + (size_t)s * EMB;
  int i0 = threadIdx.x * 8;
  float4 a = *(const float4*)(row + i0);
  float4 b = *(const float4*)(row + i0 + 4);
  float ss = a.x*a.x + a.y*a.y + a.z*a.z + a.w*a.w
           + b.x*b.x + b.y*b.y + b.z*b.z + b.w*b.w;
  #pragma unroll
  for (int off = 1; off < 64; off <<= 1) ss += __shfl_xor(ss, off);
  __shared__ float red[4];
  if ((threadIdx.x & 63) == 0) red[threadIdx.x >> 6] = ss;
  __syncthreads();
  float scale = rsqrtf((red[0] + red[1] + red[2] + red[3]) * (1.0f / EMB) + 1e-5f);
  float v[8] = {a.x, a.y, a.z, a.w, b.x, b.y, b.z, b.w};
  short8 o;
  #pragma unroll
  for (int j = 0; j < 8; ++j) o[j] = (short)f2bf(v[j] * scale);
  *(short8*)(out + (size_t)s * EMB + i0) = o;
}

// ---------------- transpose + convert (optional gate/up pair interleave) ----------------
// out row n' = (pairhalf==0) ? c : (c<pairhalf ? 2c : 2(c-pairhalf)+1)
__global__ __launch_bounds__(256) void transp_kernel(const float* __restrict__ in,
                                                     bf16u* __restrict__ out,
                                                     int R, int C, int pairhalf) {
  __shared__ float tile[32][33];
  int c0 = blockIdx.x * 32, r0 = blockIdx.y * 32;
  int tx = threadIdx.x & 31, ty = threadIdx.x >> 5;
  #pragma unroll
  for (int i = 0; i < 4; ++i)
    tile[ty + i * 8][tx] = in[(size_t)(r0 + ty + i * 8) * C + c0 + tx];
  __syncthreads();
  #pragma unroll
  for (int i = 0; i < 4; ++i) {
    int c = c0 + ty + i * 8;
    int n = pairhalf ? (c < pairhalf ? 2 * c : 2 * (c - pairhalf) + 1) : c;
    out[(size_t)n * R + r0 + tx] = f2bf(tile[tx][ty + i * 8]);
  }
}

// ---------------- RoPE ----------------
__global__ __launch_bounds__(256) void rope_kernel(const float* __restrict__ qkv,
                                                   bf16u* __restrict__ out, int col0) {
  int idx = blockIdx.x * 256 + threadIdx.x;
  int d = idx & 63;
  int s = (idx >> 6) & (SEQ - 1);
  int h = idx >> 17;
  const float* row = qkv + (size_t)s * QKV_N + col0 + h * DKH;
  float ang = (float)s * __powf(10000.0f, -(float)d * (1.0f / 64.0f));
  float si, c;
  sincosf(ang, &si, &c);
  float f0 = row[d], f1 = row[d + 64];
  bf16u* orow = out + ((size_t)h * SEQ + s) * DKH;
  orow[d]      = f2bf(c * f0 - si * f1);
  orow[d + 64] = f2bf(c * f1 + si * f0);
}

__global__ __launch_bounds__(256) void vconv_kernel(const float* __restrict__ qkv,
                                                    bf16u* __restrict__ vout) {
  int idx = blockIdx.x * 256 + threadIdx.x;
  int d = idx & 127;
  int kv = (idx >> 7) & 3;
  int s = idx >> 9;
  vout[((size_t)kv * SEQ + s) * DKH + d] = f2bf(qkv[(size_t)s * QKV_N + 2560 + kv * DKH + d]);
}

// ---------------- split-K reduce: x += p0+p1+p2+p3 ----------------
__global__ __launch_bounds__(256) void reduce4_kernel(float* __restrict__ x,
                                                      const float* __restrict__ p) {
  size_t i = ((size_t)blockIdx.x * 256 + threadIdx.x) * 4;
  const size_t MN = (size_t)SEQ * EMB;
  float4 a = *(const float4*)(x + i);
  float4 b0 = *(const float4*)(p + i);
  float4 b1 = *(const float4*)(p + i + MN);
  float4 b2 = *(const float4*)(p + i + 2 * MN);
  float4 b3 = *(const float4*)(p + i + 3 * MN);
  a.x += b0.x + b1.x + b2.x + b3.x;
  a.y += b0.y + b1.y + b2.y + b3.y;
  a.z += b0.z + b1.z + b2.z + b3.z;
  a.w += b0.w + b1.w + b2.w + b3.w;
  *(float4*)(x + i) = a;
}

// ================= 128x128 2-phase GEMM =================
// MODE 0: write bf16; MODE 1: f32 C += ; MODE 2: write f32
template <int MODE>
__global__ __launch_bounds__(256) void gemm_kernel(const bf16u* __restrict__ A,
                                                   const bf16u* __restrict__ Bt,
                                                   void* __restrict__ C,
                                                   int M, int N, int K) {
  __shared__ __align__(16) char lds[2][2][8192];

  int nx = gridDim.x, ny = gridDim.y;
  int nwg = nx * ny;
  int orig = blockIdx.y * nx + blockIdx.x;
  int q = nwg >> 3, r = nwg & 7;
  int xcd = orig & 7, loc = orig >> 3;
  int id = (xcd < r ? xcd * (q + 1) : r * (q + 1) + (xcd - r) * q) + loc;
  int bx = id / ny, by = id - bx * ny;
  int n0 = bx * 128, m0 = by * 128;

  int t = threadIdx.x;
  int w = t >> 6, l = t & 63;
  int wm = (w >> 1) * 64, wn = (w & 1) * 64;
  int l15 = l & 15, l4 = l >> 4;

  int srow = w * 16 + (l >> 2);
  int scol = (l & 3) * 8;

  f32x4 acc[4][4] = {};

  auto stage = [&](int buf, int k0) {
    #pragma unroll
    for (int i = 0; i < 2; ++i) {
      gl2lds16(A  + (size_t)(m0 + i * 64 + srow) * K + k0 + scol,
               &lds[buf][0][i * 4096 + w * 1024]);
      gl2lds16(Bt + (size_t)(n0 + i * 64 + srow) * K + k0 + scol,
               &lds[buf][1][i * 4096 + w * 1024]);
    }
  };

  auto compute = [&](int buf) {
    short8 af[4], bfr[4];
    #pragma unroll
    for (int i = 0; i < 4; ++i) {
      af[i]  = *(const short8*)(&lds[buf][0][((wm + i * 16 + l15) * 32 + l4 * 8) * 2]);
      bfr[i] = *(const short8*)(&lds[buf][1][((wn + i * 16 + l15) * 32 + l4 * 8) * 2]);
    }
    #pragma unroll
    for (int i = 0; i < 4; ++i)
      #pragma unroll
      for (int j = 0; j < 4; ++j)
        acc[i][j] = __builtin_amdgcn_mfma_f32_16x16x32_bf16(af[i], bfr[j], acc[i][j], 0, 0, 0);
  };

  int nt = K >> 5;
  int cur = 0;
  stage(0, 0);
  __syncthreads();
  for (int tt = 0; tt < nt; ++tt) {
    if (tt + 1 < nt) stage(cur ^ 1, (tt + 1) * 32);
    compute(cur);
    __syncthreads();
    cur ^= 1;
  }

  #pragma unroll
  for (int i = 0; i < 4; ++i)
    #pragma unroll
    for (int j = 0; j < 4; ++j) {
      int col = n0 + wn + j * 16 + l15;
      #pragma unroll
      for (int rr = 0; rr < 4; ++rr) {
        int row = m0 + wm + i * 16 + l4 * 4 + rr;
        float v = acc[i][j][rr];
        if (MODE == 0) {
          ((bf16u*)C)[(size_t)row * N + col] = f2bf(v);
        } else if (MODE == 1) {
          float* p = (float*)C + (size_t)row * N + col;
          *p += v;
        } else {
          ((float*)C)[(size_t)row * N + col] = v;
        }
      }
    }
}

// ================= 256x256 8-phase GEMM (T1+T2+T3+T4+T5) =================
// MODE 2: write f32 (split-K slab via blockIdx.z). MODE 3: fused SwiGLU ->
// bf16 h[row][col>>1] (wup_t must be pair-interleaved: even row = gate,
// odd row = up of the same hidden index).
__device__ __forceinline__ void stage_half(const bf16u* __restrict__ p, int ld,
                                           int row0, int k0, char* slotBase, int t) {
  int r  = t >> 3, c8 = t & 7;
  int cs = (c8 ^ (r & 7)) << 3;
  gl2lds16(p + (size_t)(row0 + r) * ld + k0 + cs, slotBase + t * 16);
  gl2lds16(p + (size_t)(row0 + 64 + r) * ld + k0 + cs, slotBase + 8192 + t * 16);
}

template<int KK>
__device__ __forceinline__ short8 read_frag(const char* slot, int row, int l4) {
  int kc = KK * 4 + l4;
  return *(const short8*)(slot + row * 128 + ((kc ^ (row & 7)) << 4));
}

template<int NH>
__device__ __forceinline__ void mfma_quad(f32x4 (&acc)[8][4], const short8 (&a)[8],
                                          short8 b0, short8 b1) {
  __builtin_amdgcn_s_setprio(1);
  #pragma unroll
  for (int mi = 0; mi < 8; ++mi) {
    acc[mi][NH * 2]     = __builtin_amdgcn_mfma_f32_16x16x32_bf16(a[mi], b0, acc[mi][NH * 2], 0, 0, 0);
    acc[mi][NH * 2 + 1] = __builtin_amdgcn_mfma_f32_16x16x32_bf16(a[mi], b1, acc[mi][NH * 2 + 1], 0, 0, 0);
  }
  __builtin_amdgcn_s_setprio(0);
}

template <int MODE>
__global__ __launch_bounds__(512) void gemm256_kernel(const bf16u* __restrict__ A,
                                                      const bf16u* __restrict__ Bt,
                                                      void* __restrict__ C,
                                                      int M, int N, int K, int ldk) {
  __shared__ __align__(16) char lds[131072];

  int koff = blockIdx.z * K;
  A  += koff;
  Bt += koff;
  float* Cz = (float*)C + (size_t)blockIdx.z * M * N;

  int nx = gridDim.x, ny = gridDim.y;
  int nwg = nx * ny;
  int orig = blockIdx.y * nx + blockIdx.x;
  int q8 = nwg >> 3, r8 = nwg & 7;
  int xcd = orig & 7, loc = orig >> 3;
  int id = (xcd < r8 ? xcd * (q8 + 1) : r8 * (q8 + 1) + (xcd - r8) * q8) + loc;
  int bx = id / ny, by = id - bx * ny;
  int n0 = bx * 256, m0 = by * 256;

  int t = threadIdx.x;
  int wid = t >> 6, lane = t & 63;
  int wr = wid >> 2, wc = wid & 3, bh = wc >> 1;
  int l15 = lane & 15, l4 = lane >> 4;

  char* AS0 = lds;              char* AS1 = lds + 16384;
  char* AS2 = lds + 32768;      char* AS3 = lds + 49152;
  char* BS0 = lds + 65536;      char* BS1 = lds + 81920;
  char* BS2 = lds + 98304;      char* BS3 = lds + 114688;

  const char* ASe = lds + wr * 16384;
  const char* ASo = ASe + 32768;
  const char* BSe = lds + 65536 + bh * 16384;
  const char* BSo = BSe + 32768;

  int brow = (wc & 1) * 64;

  f32x4 acc[8][4] = {};
  short8 a[8];
  short8 b0, b1;

  int NT = K >> 6;
  int NI = NT >> 1;

  stage_half(A,  ldk, m0,       0,  AS0, t);
  stage_half(A,  ldk, m0 + 128, 0,  AS1, t);
  stage_half(Bt, ldk, n0,       0,  BS0, t);
  stage_half(Bt, ldk, n0 + 128, 0,  BS1, t);
  stage_half(A,  ldk, m0,       64, AS2, t);
  asm volatile("s_waitcnt vmcnt(2)" ::: "memory");
  __builtin_amdgcn_s_barrier();
  __builtin_amdgcn_sched_barrier(0);

  for (int I = 0; I < NI; ++I) {
    int t0k = I * 128;
    int t1k = t0k + 64;
    bool notlast = (I + 1 < NI);

    #pragma unroll
    for (int mi = 0; mi < 8; ++mi) a[mi] = read_frag<0>(ASe, mi * 16 + l15, l4);
    b0 = read_frag<0>(BSe, brow + l15, l4);
    b1 = read_frag<0>(BSe, brow + 16 + l15, l4);
    stage_half(A, ldk, m0 + 128, t1k, AS3, t);
    __builtin_amdgcn_s_barrier();
    mfma_quad<0>(acc, a, b0, b1);
    __builtin_amdgcn_s_barrier();

    b0 = read_frag<0>(BSe, brow + 32 + l15, l4);
    b1 = read_frag<0>(BSe, brow + 48 + l15, l4);
    stage_half(Bt, ldk, n0, t1k, BS2, t);
    __builtin_amdgcn_s_barrier();
    mfma_quad<1>(acc, a, b0, b1);
    __builtin_amdgcn_s_barrier();

    #pragma unroll
    for (int mi = 0; mi < 8; ++mi) a[mi] = read_frag<1>(ASe, mi * 16 + l15, l4);
    b0 = read_frag<1>(BSe, brow + l15, l4);
    b1 = read_frag<1>(BSe, brow + 16 + l15, l4);
    stage_half(Bt, ldk, n0 + 128, t1k, BS3, t);
    __builtin_amdgcn_s_barrier();
    mfma_quad<0>(acc, a, b0, b1);
    __builtin_amdgcn_s_barrier();

    b0 = read_frag<1>(BSe, brow + 32 + l15, l4);
    b1 = read_frag<1>(BSe, brow + 48 + l15, l4);
    if (notlast) stage_half(A, ldk, m0, t0k + 128, AS0, t);
    if (notlast) { asm volatile("s_waitcnt vmcnt(2)" ::: "memory"); }
    else         { asm volatile("s_waitcnt vmcnt(0)" ::: "memory"); }
    __builtin_amdgcn_s_barrier();
    __builtin_amdgcn_sched_barrier(0);
    mfma_quad<1>(acc, a, b0, b1);
    __builtin_amdgcn_s_barrier();

    #pragma unroll
    for (int mi = 0; mi < 8; ++mi) a[mi] = read_frag<0>(ASo, mi * 16 + l15, l4);
    b0 = read_frag<0>(BSo, brow + l15, l4);
    b1 = read_frag<0>(BSo, brow + 16 + l15, l4);
    if (notlast) stage_half(A, ldk, m0 + 128, t0k + 128, AS1, t);
    __builtin_amdgcn_s_barrier();
    mfma_quad<0>(acc, a, b0, b1);
    __builtin_amdgcn_s_barrier();

    b0 = read_frag<0>(BSo, brow + 32 + l15, l4);
    b1 = read_frag<0>(BSo, brow + 48 + l15, l4);
    if (notlast) stage_half(Bt, ldk, n0, t0k + 128, BS0, t);
    __builtin_amdgcn_s_barrier();
    mfma_quad<1>(acc, a, b0, b1);
    __builtin_amdgcn_s_barrier();

    #pragma unroll
    for (int mi = 0; mi < 8; ++mi) a[mi] = read_frag<1>(ASo, mi * 16 + l15, l4);
    b0 = read_frag<1>(BSo, brow + l15, l4);
    b1 = read_frag<1>(BSo, brow + 16 + l15, l4);
    if (notlast) stage_half(Bt, ldk, n0 + 128, t0k + 128, BS1, t);
    __builtin_amdgcn_s_barrier();
    mfma_quad<0>(acc, a, b0, b1);
    __builtin_amdgcn_s_barrier();

    b0 = read_frag<1>(BSo, brow + 32 + l15, l4);
    b1 = read_frag<1>(BSo, brow + 48 + l15, l4);
    if (notlast) {
      stage_half(A, ldk, m0, t0k + 192, AS2, t);
      asm volatile("s_waitcnt vmcnt(2)" ::: "memory");
    }
    __builtin_amdgcn_s_barrier();
    __builtin_amdgcn_sched_barrier(0);
    mfma_quad<1>(acc, a, b0, b1);
    __builtin_amdgcn_s_barrier();
  }

  #pragma unroll
  for (int mi = 0; mi < 8; ++mi)
    #pragma unroll
    for (int ni = 0; ni < 4; ++ni) {
      int col = n0 + wc * 64 + ni * 16 + l15;
      #pragma unroll
      for (int rr = 0; rr < 4; ++rr) {
        int row = m0 + wr * 128 + mi * 16 + l4 * 4 + rr;
        float v = acc[mi][ni][rr];
        if (MODE == 3) {
          float pv = __shfl_xor(v, 1);   // partner column (gate<->up)
          if ((l15 & 1) == 0) {
            // even col = gate (v), odd partner = up (pv)
            float hval = pv * (v / (1.0f + __expf(-v)));
            ((bf16u*)C)[(size_t)row * HIDN + (col >> 1)] = f2bf(hval);
          }
        } else if (MODE == 2) {
          Cz[(size_t)row * N + col] = v;
        } else if (MODE == 1) {
          float* p = (float*)C + (size_t)row * N + col;
          *p += v;
        } else {
          ((bf16u*)C)[(size_t)row * N + col] = f2bf(v);
        }
      }
    }
}

// ---------------- sliding-window flash attention (KVBLK=64, defer-max) ----------------
__global__ __launch_bounds__(256) void attn_kernel(const bf16u* __restrict__ q_bf,
                                                   const bf16u* __restrict__ k_bf,
                                                   const bf16u* __restrict__ v_bf,
                                                   bf16u* __restrict__ attn_out) {
  int h = blockIdx.y;
  int q0 = blockIdx.x * 64;
  int kvh = h >> 2;
  const bf16u* Kp = k_bf + (size_t)kvh * SEQ * DKH;
  const bf16u* Vp = v_bf + (size_t)kvh * SEQ * DKH;

  __shared__ __align__(16) char  Klds[64 * 128 * 2];   // swizzled [key][dim]
  __shared__ __align__(16) bf16u Vlds[128][72];        // [dim][key] (64+8 pad)
  __shared__ __align__(16) bf16u Plds[4][16][72];      // per-wave [qrow][key]

  int t = threadIdx.x, wave = t >> 6, lane = t & 63;
  int l15 = lane & 15, l4 = lane >> 4;
  int qrow0 = q0 + wave * 16;

  short8 qf[4];
  #pragma unroll
  for (int ks = 0; ks < 4; ++ks)
    qf[ks] = *(const short8*)(q_bf + ((size_t)h * SEQ + qrow0 + l15) * DKH + ks * 32 + l4 * 8);

  f32x4 o[8] = {};
  float m[4], lsum[4];
  #pragma unroll
  for (int r = 0; r < 4; ++r) { m[r] = -INFINITY; lsum[r] = 0.0f; }

  int jstart = q0 >= WIN ? ((q0 - (WIN - 1)) & ~63) : 0;

  for (int j0 = jstart; j0 < q0 + 64; j0 += 64) {
    __syncthreads();
    // stage K (64x128, XOR-swizzled rows)
    #pragma unroll
    for (int i = 0; i < 4; ++i) {
      int c = t + i * 256;
      int key = c >> 4, cc = c & 15;
      int off = key * 256 + cc * 16; off ^= (key & 7) << 4;
      *(short8*)(Klds + off) = *(const short8*)(Kp + (size_t)(j0 + key) * DKH + cc * 8);
    }
    // stage V transposed
    #pragma unroll
    for (int hh = 0; hh < 2; ++hh) {
      int key = hh * 32 + (t >> 3), d0 = (t & 7) * 16;
      const bf16u* src = Vp + (size_t)(j0 + key) * DKH + d0;
      #pragma unroll
      for (int i = 0; i < 16; ++i) Vlds[d0 + i][key] = src[i];
    }
    __syncthreads();

    // S = Q K^T (four 16-key tiles)
    f32x4 sacc[4] = {};
    #pragma unroll
    for (int nt = 0; nt < 4; ++nt) {
      int key = nt * 16 + l15;
      #pragma unroll
      for (int ks = 0; ks < 4; ++ks) {
        int off = key * 256 + ks * 64 + l4 * 16; off ^= (key & 7) << 4;
        short8 kf = *(short8*)(Klds + off);
        sacc[nt] = __builtin_amdgcn_mfma_f32_16x16x32_bf16(qf[ks], kf, sacc[nt], 0, 0, 0);
      }
    }

    // mask + scale
    float sv[4][4];
    #pragma unroll
    for (int nt = 0; nt < 4; ++nt) {
      int jk = j0 + nt * 16 + l15;
      #pragma unroll
      for (int r = 0; r < 4; ++r) {
        int iq = qrow0 + l4 * 4 + r;
        float s = sacc[nt][r] * 0.08838834764831845f;
        bool valid = (jk <= iq) && (iq - jk < WIN);
        sv[nt][r] = valid ? s : -1e9f;
      }
    }

    // tile max per row
    float mxr[4];
    #pragma unroll
    for (int r = 0; r < 4; ++r) {
      float mx = fmaxf(fmaxf(sv[0][r], sv[1][r]), fmaxf(sv[2][r], sv[3][r]));
      #pragma unroll
      for (int off = 1; off < 16; off <<= 1) mx = fmaxf(mx, __shfl_xor(mx, off));
      mxr[r] = mx;
    }

    // defer-max: only rescale when some row's max grew by > 8
    bool grow = (mxr[0] > m[0] + 8.0f) || (mxr[1] > m[1] + 8.0f) ||
                (mxr[2] > m[2] + 8.0f) || (mxr[3] > m[3] + 8.0f);
    if (__any(grow)) {
      #pragma unroll
      for (int r = 0; r < 4; ++r) {
        float mn = fmaxf(m[r], mxr[r]);
        float alpha = __expf(m[r] - mn);
        m[r] = mn;
        lsum[r] *= alpha;
        #pragma unroll
        for (int d = 0; d < 8; ++d) o[d][r] *= alpha;
      }
    }

    // P = exp(S - m), row-sum
    float p[4][4];
    #pragma unroll
    for (int r = 0; r < 4; ++r) {
      float ps = 0.0f;
      #pragma unroll
      for (int nt = 0; nt < 4; ++nt) { p[nt][r] = __expf(sv[nt][r] - m[r]); ps += p[nt][r]; }
      #pragma unroll
      for (int off = 1; off < 16; off <<= 1) ps += __shfl_xor(ps, off);
      lsum[r] += ps;
    }

    // write P -> per-wave LDS (bf16), then PV over two 32-key halves
    #pragma unroll
    for (int nt = 0; nt < 4; ++nt)
      #pragma unroll
      for (int r = 0; r < 4; ++r)
        Plds[wave][l4 * 4 + r][nt * 16 + l15] = f2bf(p[nt][r]);

    #pragma unroll
    for (int kk = 0; kk < 2; ++kk) {
      short8 pf = *(short8*)(&Plds[wave][l15][kk * 32 + l4 * 8]);
      #pragma unroll
      for (int d = 0; d < 8; ++d) {
        short8 vf = *(short8*)(&Vlds[d * 16 + l15][kk * 32 + l4 * 8]);
        o[d] = __builtin_amdgcn_mfma_f32_16x16x32_bf16(pf, vf, o[d], 0, 0, 0);
      }
    }
  }

  #pragma unroll
  for (int d = 0; d < 8; ++d)
    #pragma unroll
    for (int r = 0; r < 4; ++r) {
      int row = qrow0 + l4 * 4 + r;
      attn_out[(size_t)row * (NHEAD * DKH) + h * DKH + d * 16 + l15] = f2bf(o[d][r] / lsum[r]);
    }
}

// ---------------- host ----------------
extern "C" void kernel_launch(void* const* d_in, const int* in_sizes, int n_in,
                              void* d_out, int out_size, void* d_ws, size_t ws_size,
                              hipStream_t stream) {
  const int*   tokens  = (const int*)d_in[0];
  const float* table   = (const float*)d_in[1];
  const float* wq      = (const float*)d_in[2];
  const float* wk      = (const float*)d_in[3];
  const float* wv      = (const float*)d_in[4];
  const float* wo      = (const float*)d_in[5];
  const float* w_up    = (const float*)d_in[6];
  const float* w_down  = (const float*)d_in[7];
  const float* w_vocab = (const float*)d_in[8];
  float* out = (float*)d_out;

  char* base = (char*)d_ws;
  size_t o = 0;
  auto alloc = [&](size_t bytes) { size_t r = o; o += (bytes + 255) & ~(size_t)255; return r; };
  size_t o_x     = alloc((size_t)SEQ * EMB * 4);
  size_t o_nbf   = alloc((size_t)SEQ * EMB * 2);
  size_t o_qkvw  = alloc((size_t)QKV_N * EMB * 2);
  size_t o_wot   = alloc((size_t)EMB * EMB * 2);
  size_t o_wupt  = alloc((size_t)2 * HIDN * EMB * 2);
  size_t o_wdnt  = alloc((size_t)EMB * HIDN * 2);
  size_t o_qkvf  = alloc((size_t)SEQ * QKV_N * 4);
  size_t o_qbf   = alloc((size_t)NHEAD * SEQ * DKH * 2);
  size_t o_kbf   = alloc((size_t)NKV * SEQ * DKH * 2);
  size_t o_vbf   = alloc((size_t)NKV * SEQ * DKH * 2);
  size_t o_attn  = alloc((size_t)SEQ * EMB * 2);
  size_t o_big   = alloc((size_t)SEQ * 2 * HIDN * 4);   // split-K partials / wvoc_t
  size_t o_hbf   = alloc((size_t)SEQ * HIDN * 2);

  float* x      = (float*)(base + o_x);
  bf16u* n_bf   = (bf16u*)(base + o_nbf);
  bf16u* qkvw_t = (bf16u*)(base + o_qkvw);
  bf16u* wo_t   = (bf16u*)(base + o_wot);
  bf16u* wup_t  = (bf16u*)(base + o_wupt);
  bf16u* wdn_t  = (bf16u*)(base + o_wdnt);
  float* qkv_f  = (float*)(base + o_qkvf);
  bf16u* q_bf   = (bf16u*)(base + o_qbf);
  bf16u* k_bf   = (bf16u*)(base + o_kbf);
  bf16u* v_bf   = (bf16u*)(base + o_vbf);
  bf16u* attn_b = (bf16u*)(base + o_attn);
  float* part   = (float*)(base + o_big);
  bf16u* h_bf   = (bf16u*)(base + o_hbf);
  bf16u* wvoc_t = (bf16u*)(base + o_big);

  embed_kernel<<<SEQ, 256, 0, stream>>>(tokens, table, x);

  for (int l = 0; l < NLAY; ++l) {
    transp_kernel<<<dim3(EMB / 32, EMB / 32), 256, 0, stream>>>(
        wq + (size_t)l * EMB * EMB, qkvw_t, EMB, EMB, 0);
    transp_kernel<<<dim3(512 / 32, EMB / 32), 256, 0, stream>>>(
        wk + (size_t)l * EMB * 512, qkvw_t + (size_t)2048 * EMB, EMB, 512, 0);
    transp_kernel<<<dim3(512 / 32, EMB / 32), 256, 0, stream>>>(
        wv + (size_t)l * EMB * 512, qkvw_t + (size_t)2560 * EMB, EMB, 512, 0);
    transp_kernel<<<dim3(EMB / 32, EMB / 32), 256, 0, stream>>>(
        wo + (size_t)l * EMB * EMB, wo_t, EMB, EMB, 0);
    // pair-interleaved: row 2j = gate col j, row 2j+1 = up col j
    transp_kernel<<<dim3(2 * HIDN / 32, EMB / 32), 256, 0, stream>>>(
        w_up + (size_t)l * EMB * 2 * HIDN, wup_t, EMB, 2 * HIDN, HIDN);
    transp_kernel<<<dim3(EMB / 32, HIDN / 32), 256, 0, stream>>>(
        w_down + (size_t)l * HIDN * EMB, wdn_t, HIDN, EMB, 0);

    rmsnorm_kernel<<<SEQ, 256, 0, stream>>>(x, n_bf);
    gemm_kernel<2><<<dim3(QKV_N / 128, SEQ / 128), 256, 0, stream>>>(
        n_bf, qkvw_t, qkv_f, SEQ, QKV_N, EMB);

    rope_kernel<<<NHEAD * SEQ * 64 / 256, 256, 0, stream>>>(qkv_f, q_bf, 0);
    rope_kernel<<<NKV * SEQ * 64 / 256, 256, 0, stream>>>(qkv_f, k_bf, 2048);
    vconv_kernel<<<NKV * SEQ * 128 / 256, 256, 0, stream>>>(qkv_f, v_bf);

    attn_kernel<<<dim3(SEQ / 64, NHEAD), 256, 0, stream>>>(q_bf, k_bf, v_bf, attn_b);

    gemm_kernel<1><<<dim3(EMB / 128, SEQ / 128), 256, 0, stream>>>(
        attn_b, wo_t, x, SEQ, EMB, EMB);

    rmsnorm_kernel<<<SEQ, 256, 0, stream>>>(x, n_bf);
    // up-proj fused with SwiGLU -> h_bf
    gemm256_kernel<3><<<dim3(2 * HIDN / 256, SEQ / 256), 512, 0, stream>>>(
        n_bf, wup_t, h_bf, SEQ, 2 * HIDN, EMB, EMB);
    // down: 4-way split-K, then x += sum(partials)
    gemm256_kernel<2><<<dim3(EMB / 256, SEQ / 256, 4), 512, 0, stream>>>(
        h_bf, wdn_t, part, SEQ, EMB, 2048, HIDN);
    reduce4_kernel<<<SEQ * EMB / 1024, 256, 0, stream>>>(x, part);
  }

  transp_kernel<<<dim3(NVOC / 32, EMB / 32), 256, 0, stream>>>(w_vocab, wvoc_t, EMB, NVOC, 0);
  rmsnorm_kernel<<<SEQ, 256, 0, stream>>>(x, n_bf);
  gemm256_kernel<2><<<dim3(NVOC / 256, SEQ / 256), 512, 0, stream>>>(
      n_bf, wvoc_t, out, SEQ, NVOC, EMB, EMB);
}

// Round 6
// 2495.086 us; speedup vs baseline: 1.4169x; 1.0039x over previous
//
#include <hip/hip_runtime.h>
#include <cstdint>

typedef unsigned short bf16u;
typedef __attribute__((ext_vector_type(8))) short short8;
typedef __attribute__((ext_vector_type(4))) short short4v;
typedef __attribute__((ext_vector_type(4))) float f32x4;

#define SEQ   2048
#define EMB   2048
#define NHEAD 16
#define NKV   4
#define DKH   128
#define HIDN  8192
#define NVOC  32000
#define NLAY  4
#define WIN   1024
#define QKV_N 3072

__device__ __forceinline__ bf16u f2bf(float f) {
  union { float f; uint32_t u; } v; v.f = f;
  uint32_t r = v.u + 0x7FFFu + ((v.u >> 16) & 1u);
  return (bf16u)(r >> 16);
}

__device__ __forceinline__ void gl2lds16(const void* g, void* l) {
  __builtin_amdgcn_global_load_lds(
      (const __attribute__((address_space(1))) void*)g,
      (__attribute__((address_space(3))) void*)l, 16, 0, 0);
}

// ---------------- embedding ----------------
__global__ __launch_bounds__(256) void embed_kernel(const int* __restrict__ tokens,
                                                    const float* __restrict__ table,
                                                    float* __restrict__ x) {
  int s = blockIdx.x;
  int tok = tokens[s];
  int i0 = threadIdx.x * 8;
  float4 a = {0,0,0,0}, b = {0,0,0,0};
  if (tok != 0) {
    const float* src = table + (size_t)tok * EMB;
    a = *(const float4*)(src + i0);
    b = *(const float4*)(src + i0 + 4);
  }
  *(float4*)(x + (size_t)s * EMB + i0) = a;
  *(float4*)(x + (size_t)s * EMB + i0 + 4) = b;
}

// ---------------- rmsnorm (standalone) ----------------
__global__ __launch_bounds__(256) void rmsnorm_kernel(const float* __restrict__ x,
                                                      bf16u* __restrict__ out) {
  int s = blockIdx.x;
  const float* row = x + (size_t)s * EMB;
  int i0 = threadIdx.x * 8;
  float4 a = *(const float4*)(row + i0);
  float4 b = *(const float4*)(row + i0 + 4);
  float ss = a.x*a.x + a.y*a.y + a.z*a.z + a.w*a.w
           + b.x*b.x + b.y*b.y + b.z*b.z + b.w*b.w;
  #pragma unroll
  for (int off = 1; off < 64; off <<= 1) ss += __shfl_xor(ss, off);
  __shared__ float red[4];
  if ((threadIdx.x & 63) == 0) red[threadIdx.x >> 6] = ss;
  __syncthreads();
  float scale = rsqrtf((red[0] + red[1] + red[2] + red[3]) * (1.0f / EMB) + 1e-5f);
  float v[8] = {a.x, a.y, a.z, a.w, b.x, b.y, b.z, b.w};
  short8 o;
  #pragma unroll
  for (int j = 0; j < 8; ++j) o[j] = (short)f2bf(v[j] * scale);
  *(short8*)(out + (size_t)s * EMB + i0) = o;
}

// ---------------- fused split-K reduce + residual + rmsnorm ----------------
// x[row] += p0+p1+p2+p3 ; n_bf[row] = rmsnorm(x[row])
__global__ __launch_bounds__(256) void reduce4norm_kernel(float* __restrict__ x,
                                                          const float* __restrict__ p,
                                                          bf16u* __restrict__ nout) {
  int s = blockIdx.x;
  const size_t MN = (size_t)SEQ * EMB;
  size_t base = (size_t)s * EMB + threadIdx.x * 8;
  float v[8];
  #pragma unroll
  for (int h = 0; h < 2; ++h) {
    size_t i = base + h * 4;
    float4 a  = *(const float4*)(x + i);
    float4 b0 = *(const float4*)(p + i);
    float4 b1 = *(const float4*)(p + i + MN);
    float4 b2 = *(const float4*)(p + i + 2 * MN);
    float4 b3 = *(const float4*)(p + i + 3 * MN);
    v[h*4+0] = a.x + b0.x + b1.x + b2.x + b3.x;
    v[h*4+1] = a.y + b0.y + b1.y + b2.y + b3.y;
    v[h*4+2] = a.z + b0.z + b1.z + b2.z + b3.z;
    v[h*4+3] = a.w + b0.w + b1.w + b2.w + b3.w;
    *(float4*)(x + i) = make_float4(v[h*4+0], v[h*4+1], v[h*4+2], v[h*4+3]);
  }
  float ss = 0.0f;
  #pragma unroll
  for (int j = 0; j < 8; ++j) ss += v[j] * v[j];
  #pragma unroll
  for (int off = 1; off < 64; off <<= 1) ss += __shfl_xor(ss, off);
  __shared__ float red[4];
  if ((threadIdx.x & 63) == 0) red[threadIdx.x >> 6] = ss;
  __syncthreads();
  float scale = rsqrtf((red[0] + red[1] + red[2] + red[3]) * (1.0f / EMB) + 1e-5f);
  short8 o;
  #pragma unroll
  for (int j = 0; j < 8; ++j) o[j] = (short)f2bf(v[j] * scale);
  *(short8*)(nout + base) = o;
}

// ---------------- transpose + convert, 64x64 tiles, vectorized both sides ----------------
// in[R][C] f32 -> out[n(c)][R] bf16 ; n(c) = pairhalf? interleave : c
__global__ __launch_bounds__(256) void transp_kernel(const float* __restrict__ in,
                                                     bf16u* __restrict__ out,
                                                     int R, int C, int pairhalf) {
  __shared__ float tile[64][65];   // [c][r]
  int c0 = blockIdx.x * 64, r0 = blockIdx.y * 64;
  int tx = threadIdx.x & 15, ty = threadIdx.x >> 4;
  #pragma unroll
  for (int i = 0; i < 4; ++i) {
    int r = ty + i * 16;
    float4 v = *(const float4*)(in + (size_t)(r0 + r) * C + c0 + tx * 4);
    tile[tx * 4 + 0][r] = v.x;
    tile[tx * 4 + 1][r] = v.y;
    tile[tx * 4 + 2][r] = v.z;
    tile[tx * 4 + 3][r] = v.w;
  }
  __syncthreads();
  int rx = threadIdx.x & 15, cy = threadIdx.x >> 4;
  #pragma unroll
  for (int i = 0; i < 4; ++i) {
    int c = c0 + cy + i * 16;
    int n = pairhalf ? (c < pairhalf ? 2 * c : 2 * (c - pairhalf) + 1) : c;
    short4v o;
    #pragma unroll
    for (int j = 0; j < 4; ++j) o[j] = (short)f2bf(tile[cy + i * 16][rx * 4 + j]);
    *(short4v*)(out + (size_t)n * R + r0 + rx * 4) = o;
  }
}

// ---------------- RoPE ----------------
__global__ __launch_bounds__(256) void rope_kernel(const float* __restrict__ qkv,
                                                   bf16u* __restrict__ out, int col0) {
  int idx = blockIdx.x * 256 + threadIdx.x;
  int d = idx & 63;
  int s = (idx >> 6) & (SEQ - 1);
  int h = idx >> 17;
  const float* row = qkv + (size_t)s * QKV_N + col0 + h * DKH;
  float ang = (float)s * __powf(10000.0f, -(float)d * (1.0f / 64.0f));
  float si, c;
  sincosf(ang, &si, &c);
  float f0 = row[d], f1 = row[d + 64];
  bf16u* orow = out + ((size_t)h * SEQ + s) * DKH;
  orow[d]      = f2bf(c * f0 - si * f1);
  orow[d + 64] = f2bf(c * f1 + si * f0);
}

__global__ __launch_bounds__(256) void vconv_kernel(const float* __restrict__ qkv,
                                                    bf16u* __restrict__ vout) {
  int idx = blockIdx.x * 256 + threadIdx.x;
  int d = idx & 127;
  int kv = (idx >> 7) & 3;
  int s = idx >> 9;
  vout[((size_t)kv * SEQ + s) * DKH + d] = f2bf(qkv[(size_t)s * QKV_N + 2560 + kv * DKH + d]);
}

// ================= 128x128 2-phase GEMM =================
// MODE 0: write bf16; MODE 1: f32 C += ; MODE 2: write f32
template <int MODE>
__global__ __launch_bounds__(256) void gemm_kernel(const bf16u* __restrict__ A,
                                                   const bf16u* __restrict__ Bt,
                                                   void* __restrict__ C,
                                                   int M, int N, int K) {
  __shared__ __align__(16) char lds[2][2][8192];

  int nx = gridDim.x, ny = gridDim.y;
  int nwg = nx * ny;
  int orig = blockIdx.y * nx + blockIdx.x;
  int q = nwg >> 3, r = nwg & 7;
  int xcd = orig & 7, loc = orig >> 3;
  int id = (xcd < r ? xcd * (q + 1) : r * (q + 1) + (xcd - r) * q) + loc;
  int bx = id / ny, by = id - bx * ny;
  int n0 = bx * 128, m0 = by * 128;

  int t = threadIdx.x;
  int w = t >> 6, l = t & 63;
  int wm = (w >> 1) * 64, wn = (w & 1) * 64;
  int l15 = l & 15, l4 = l >> 4;

  int srow = w * 16 + (l >> 2);
  int scol = (l & 3) * 8;

  f32x4 acc[4][4] = {};

  auto stage = [&](int buf, int k0) {
    #pragma unroll
    for (int i = 0; i < 2; ++i) {
      gl2lds16(A  + (size_t)(m0 + i * 64 + srow) * K + k0 + scol,
               &lds[buf][0][i * 4096 + w * 1024]);
      gl2lds16(Bt + (size_t)(n0 + i * 64 + srow) * K + k0 + scol,
               &lds[buf][1][i * 4096 + w * 1024]);
    }
  };

  auto compute = [&](int buf) {
    short8 af[4], bfr[4];
    #pragma unroll
    for (int i = 0; i < 4; ++i) {
      af[i]  = *(const short8*)(&lds[buf][0][((wm + i * 16 + l15) * 32 + l4 * 8) * 2]);
      bfr[i] = *(const short8*)(&lds[buf][1][((wn + i * 16 + l15) * 32 + l4 * 8) * 2]);
    }
    #pragma unroll
    for (int i = 0; i < 4; ++i)
      #pragma unroll
      for (int j = 0; j < 4; ++j)
        acc[i][j] = __builtin_amdgcn_mfma_f32_16x16x32_bf16(af[i], bfr[j], acc[i][j], 0, 0, 0);
  };

  int nt = K >> 5;
  int cur = 0;
  stage(0, 0);
  __syncthreads();
  for (int tt = 0; tt < nt; ++tt) {
    if (tt + 1 < nt) stage(cur ^ 1, (tt + 1) * 32);
    compute(cur);
    __syncthreads();
    cur ^= 1;
  }

  #pragma unroll
  for (int i = 0; i < 4; ++i)
    #pragma unroll
    for (int j = 0; j < 4; ++j) {
      int col = n0 + wn + j * 16 + l15;
      #pragma unroll
      for (int rr = 0; rr < 4; ++rr) {
        int row = m0 + wm + i * 16 + l4 * 4 + rr;
        float v = acc[i][j][rr];
        if (MODE == 0) {
          ((bf16u*)C)[(size_t)row * N + col] = f2bf(v);
        } else if (MODE == 1) {
          float* p = (float*)C + (size_t)row * N + col;
          *p += v;
        } else {
          ((float*)C)[(size_t)row * N + col] = v;
        }
      }
    }
}

// ================= 256x256 8-phase GEMM (T1+T2+T3+T4+T5) =================
// MODE 2: write f32 (split-K slab via blockIdx.z). MODE 3: fused SwiGLU ->
// bf16 h[row][col>>1] (wup_t pair-interleaved: even row = gate, odd = up).
__device__ __forceinline__ void stage_half(const bf16u* __restrict__ p, int ld,
                                           int row0, int k0, char* slotBase, int t) {
  int r  = t >> 3, c8 = t & 7;
  int cs = (c8 ^ (r & 7)) << 3;
  gl2lds16(p + (size_t)(row0 + r) * ld + k0 + cs, slotBase + t * 16);
  gl2lds16(p + (size_t)(row0 + 64 + r) * ld + k0 + cs, slotBase + 8192 + t * 16);
}

template<int KK>
__device__ __forceinline__ short8 read_frag(const char* slot, int row, int l4) {
  int kc = KK * 4 + l4;
  return *(const short8*)(slot + row * 128 + ((kc ^ (row & 7)) << 4));
}

template<int NH>
__device__ __forceinline__ void mfma_quad(f32x4 (&acc)[8][4], const short8 (&a)[8],
                                          short8 b0, short8 b1) {
  __builtin_amdgcn_s_setprio(1);
  #pragma unroll
  for (int mi = 0; mi < 8; ++mi) {
    acc[mi][NH * 2]     = __builtin_amdgcn_mfma_f32_16x16x32_bf16(a[mi], b0, acc[mi][NH * 2], 0, 0, 0);
    acc[mi][NH * 2 + 1] = __builtin_amdgcn_mfma_f32_16x16x32_bf16(a[mi], b1, acc[mi][NH * 2 + 1], 0, 0, 0);
  }
  __builtin_amdgcn_s_setprio(0);
}

template <int MODE>
__global__ __launch_bounds__(512) void gemm256_kernel(const bf16u* __restrict__ A,
                                                      const bf16u* __restrict__ Bt,
                                                      void* __restrict__ C,
                                                      int M, int N, int K, int ldk) {
  __shared__ __align__(16) char lds[131072];

  int koff = blockIdx.z * K;
  A  += koff;
  Bt += koff;
  float* Cz = (float*)C + (size_t)blockIdx.z * M * N;

  int nx = gridDim.x, ny = gridDim.y;
  int nwg = nx * ny;
  int orig = blockIdx.y * nx + blockIdx.x;
  int q8 = nwg >> 3, r8 = nwg & 7;
  int xcd = orig & 7, loc = orig >> 3;
  int id = (xcd < r8 ? xcd * (q8 + 1) : r8 * (q8 + 1) + (xcd - r8) * q8) + loc;
  int bx = id / ny, by = id - bx * ny;
  int n0 = bx * 256, m0 = by * 256;

  int t = threadIdx.x;
  int wid = t >> 6, lane = t & 63;
  int wr = wid >> 2, wc = wid & 3, bh = wc >> 1;
  int l15 = lane & 15, l4 = lane >> 4;

  char* AS0 = lds;              char* AS1 = lds + 16384;
  char* AS2 = lds + 32768;      char* AS3 = lds + 49152;
  char* BS0 = lds + 65536;      char* BS1 = lds + 81920;
  char* BS2 = lds + 98304;      char* BS3 = lds + 114688;

  const char* ASe = lds + wr * 16384;
  const char* ASo = ASe + 32768;
  const char* BSe = lds + 65536 + bh * 16384;
  const char* BSo = BSe + 32768;

  int brow = (wc & 1) * 64;

  f32x4 acc[8][4] = {};
  short8 a[8];
  short8 b0, b1;

  int NT = K >> 6;
  int NI = NT >> 1;

  stage_half(A,  ldk, m0,       0,  AS0, t);
  stage_half(A,  ldk, m0 + 128, 0,  AS1, t);
  stage_half(Bt, ldk, n0,       0,  BS0, t);
  stage_half(Bt, ldk, n0 + 128, 0,  BS1, t);
  stage_half(A,  ldk, m0,       64, AS2, t);
  asm volatile("s_waitcnt vmcnt(2)" ::: "memory");
  __builtin_amdgcn_s_barrier();
  __builtin_amdgcn_sched_barrier(0);

  for (int I = 0; I < NI; ++I) {
    int t0k = I * 128;
    int t1k = t0k + 64;
    bool notlast = (I + 1 < NI);

    #pragma unroll
    for (int mi = 0; mi < 8; ++mi) a[mi] = read_frag<0>(ASe, mi * 16 + l15, l4);
    b0 = read_frag<0>(BSe, brow + l15, l4);
    b1 = read_frag<0>(BSe, brow + 16 + l15, l4);
    stage_half(A, ldk, m0 + 128, t1k, AS3, t);
    __builtin_amdgcn_s_barrier();
    mfma_quad<0>(acc, a, b0, b1);
    __builtin_amdgcn_s_barrier();

    b0 = read_frag<0>(BSe, brow + 32 + l15, l4);
    b1 = read_frag<0>(BSe, brow + 48 + l15, l4);
    stage_half(Bt, ldk, n0, t1k, BS2, t);
    __builtin_amdgcn_s_barrier();
    mfma_quad<1>(acc, a, b0, b1);
    __builtin_amdgcn_s_barrier();

    #pragma unroll
    for (int mi = 0; mi < 8; ++mi) a[mi] = read_frag<1>(ASe, mi * 16 + l15, l4);
    b0 = read_frag<1>(BSe, brow + l15, l4);
    b1 = read_frag<1>(BSe, brow + 16 + l15, l4);
    stage_half(Bt, ldk, n0 + 128, t1k, BS3, t);
    __builtin_amdgcn_s_barrier();
    mfma_quad<0>(acc, a, b0, b1);
    __builtin_amdgcn_s_barrier();

    b0 = read_frag<1>(BSe, brow + 32 + l15, l4);
    b1 = read_frag<1>(BSe, brow + 48 + l15, l4);
    if (notlast) stage_half(A, ldk, m0, t0k + 128, AS0, t);
    if (notlast) { asm volatile("s_waitcnt vmcnt(2)" ::: "memory"); }
    else         { asm volatile("s_waitcnt vmcnt(0)" ::: "memory"); }
    __builtin_amdgcn_s_barrier();
    __builtin_amdgcn_sched_barrier(0);
    mfma_quad<1>(acc, a, b0, b1);
    __builtin_amdgcn_s_barrier();

    #pragma unroll
    for (int mi = 0; mi < 8; ++mi) a[mi] = read_frag<0>(ASo, mi * 16 + l15, l4);
    b0 = read_frag<0>(BSo, brow + l15, l4);
    b1 = read_frag<0>(BSo, brow + 16 + l15, l4);
    if (notlast) stage_half(A, ldk, m0 + 128, t0k + 128, AS1, t);
    __builtin_amdgcn_s_barrier();
    mfma_quad<0>(acc, a, b0, b1);
    __builtin_amdgcn_s_barrier();

    b0 = read_frag<0>(BSo, brow + 32 + l15, l4);
    b1 = read_frag<0>(BSo, brow + 48 + l15, l4);
    if (notlast) stage_half(Bt, ldk, n0, t0k + 128, BS0, t);
    __builtin_amdgcn_s_barrier();
    mfma_quad<1>(acc, a, b0, b1);
    __builtin_amdgcn_s_barrier();

    #pragma unroll
    for (int mi = 0; mi < 8; ++mi) a[mi] = read_frag<1>(ASo, mi * 16 + l15, l4);
    b0 = read_frag<1>(BSo, brow + l15, l4);
    b1 = read_frag<1>(BSo, brow + 16 + l15, l4);
    if (notlast) stage_half(Bt, ldk, n0 + 128, t0k + 128, BS1, t);
    __builtin_amdgcn_s_barrier();
    mfma_quad<0>(acc, a, b0, b1);
    __builtin_amdgcn_s_barrier();

    b0 = read_frag<1>(BSo, brow + 32 + l15, l4);
    b1 = read_frag<1>(BSo, brow + 48 + l15, l4);
    if (notlast) {
      stage_half(A, ldk, m0, t0k + 192, AS2, t);
      asm volatile("s_waitcnt vmcnt(2)" ::: "memory");
    }
    __builtin_amdgcn_s_barrier();
    __builtin_amdgcn_sched_barrier(0);
    mfma_quad<1>(acc, a, b0, b1);
    __builtin_amdgcn_s_barrier();
  }

  #pragma unroll
  for (int mi = 0; mi < 8; ++mi)
    #pragma unroll
    for (int ni = 0; ni < 4; ++ni) {
      int col = n0 + wc * 64 + ni * 16 + l15;
      #pragma unroll
      for (int rr = 0; rr < 4; ++rr) {
        int row = m0 + wr * 128 + mi * 16 + l4 * 4 + rr;
        float v = acc[mi][ni][rr];
        if (MODE == 3) {
          float pv = __shfl_xor(v, 1);
          if ((l15 & 1) == 0) {
            float hval = pv * (v / (1.0f + __expf(-v)));
            ((bf16u*)C)[(size_t)row * HIDN + (col >> 1)] = f2bf(hval);
          }
        } else if (MODE == 2) {
          Cz[(size_t)row * N + col] = v;
        } else if (MODE == 1) {
          float* p = (float*)C + (size_t)row * N + col;
          *p += v;
        } else {
          ((bf16u*)C)[(size_t)row * N + col] = f2bf(v);
        }
      }
    }
}

// ---------------- sliding-window flash attention (KVBLK=64, defer-max) ----------------
__global__ __launch_bounds__(256) void attn_kernel(const bf16u* __restrict__ q_bf,
                                                   const bf16u* __restrict__ k_bf,
                                                   const bf16u* __restrict__ v_bf,
                                                   bf16u* __restrict__ attn_out) {
  int h = blockIdx.y;
  int q0 = blockIdx.x * 64;
  int kvh = h >> 2;
  const bf16u* Kp = k_bf + (size_t)kvh * SEQ * DKH;
  const bf16u* Vp = v_bf + (size_t)kvh * SEQ * DKH;

  __shared__ __align__(16) char  Klds[64 * 128 * 2];
  __shared__ __align__(16) bf16u Vlds[128][72];
  __shared__ __align__(16) bf16u Plds[4][16][72];

  int t = threadIdx.x, wave = t >> 6, lane = t & 63;
  int l15 = lane & 15, l4 = lane >> 4;
  int qrow0 = q0 + wave * 16;

  short8 qf[4];
  #pragma unroll
  for (int ks = 0; ks < 4; ++ks)
    qf[ks] = *(const short8*)(q_bf + ((size_t)h * SEQ + qrow0 + l15) * DKH + ks * 32 + l4 * 8);

  f32x4 o[8] = {};
  float m[4], lsum[4];
  #pragma unroll
  for (int r = 0; r < 4; ++r) { m[r] = -INFINITY; lsum[r] = 0.0f; }

  int jstart = q0 >= WIN ? ((q0 - (WIN - 1)) & ~63) : 0;

  for (int j0 = jstart; j0 < q0 + 64; j0 += 64) {
    __syncthreads();
    #pragma unroll
    for (int i = 0; i < 4; ++i) {
      int c = t + i * 256;
      int key = c >> 4, cc = c & 15;
      int off = key * 256 + cc * 16; off ^= (key & 7) << 4;
      *(short8*)(Klds + off) = *(const short8*)(Kp + (size_t)(j0 + key) * DKH + cc * 8);
    }
    #pragma unroll
    for (int hh = 0; hh < 2; ++hh) {
      int key = hh * 32 + (t >> 3), d0 = (t & 7) * 16;
      const bf16u* src = Vp + (size_t)(j0 + key) * DKH + d0;
      #pragma unroll
      for (int i = 0; i < 16; ++i) Vlds[d0 + i][key] = src[i];
    }
    __syncthreads();

    f32x4 sacc[4] = {};
    #pragma unroll
    for (int nt = 0; nt < 4; ++nt) {
      int key = nt * 16 + l15;
      #pragma unroll
      for (int ks = 0; ks < 4; ++ks) {
        int off = key * 256 + ks * 64 + l4 * 16; off ^= (key & 7) << 4;
        short8 kf = *(short8*)(Klds + off);
        sacc[nt] = __builtin_amdgcn_mfma_f32_16x16x32_bf16(qf[ks], kf, sacc[nt], 0, 0, 0);
      }
    }

    float sv[4][4];
    #pragma unroll
    for (int nt = 0; nt < 4; ++nt) {
      int jk = j0 + nt * 16 + l15;
      #pragma unroll
      for (int r = 0; r < 4; ++r) {
        int iq = qrow0 + l4 * 4 + r;
        float s = sacc[nt][r] * 0.08838834764831845f;
        bool valid = (jk <= iq) && (iq - jk < WIN);
        sv[nt][r] = valid ? s : -1e9f;
      }
    }

    float mxr[4];
    #pragma unroll
    for (int r = 0; r < 4; ++r) {
      float mx = fmaxf(fmaxf(sv[0][r], sv[1][r]), fmaxf(sv[2][r], sv[3][r]));
      #pragma unroll
      for (int off = 1; off < 16; off <<= 1) mx = fmaxf(mx, __shfl_xor(mx, off));
      mxr[r] = mx;
    }

    bool grow = (mxr[0] > m[0] + 8.0f) || (mxr[1] > m[1] + 8.0f) ||
                (mxr[2] > m[2] + 8.0f) || (mxr[3] > m[3] + 8.0f);
    if (__any(grow)) {
      #pragma unroll
      for (int r = 0; r < 4; ++r) {
        float mn = fmaxf(m[r], mxr[r]);
        float alpha = __expf(m[r] - mn);
        m[r] = mn;
        lsum[r] *= alpha;
        #pragma unroll
        for (int d = 0; d < 8; ++d) o[d][r] *= alpha;
      }
    }

    float p[4][4];
    #pragma unroll
    for (int r = 0; r < 4; ++r) {
      float ps = 0.0f;
      #pragma unroll
      for (int nt = 0; nt < 4; ++nt) { p[nt][r] = __expf(sv[nt][r] - m[r]); ps += p[nt][r]; }
      #pragma unroll
      for (int off = 1; off < 16; off <<= 1) ps += __shfl_xor(ps, off);
      lsum[r] += ps;
    }

    #pragma unroll
    for (int nt = 0; nt < 4; ++nt)
      #pragma unroll
      for (int r = 0; r < 4; ++r)
        Plds[wave][l4 * 4 + r][nt * 16 + l15] = f2bf(p[nt][r]);

    #pragma unroll
    for (int kk = 0; kk < 2; ++kk) {
      short8 pf = *(short8*)(&Plds[wave][l15][kk * 32 + l4 * 8]);
      #pragma unroll
      for (int d = 0; d < 8; ++d) {
        short8 vf = *(short8*)(&Vlds[d * 16 + l15][kk * 32 + l4 * 8]);
        o[d] = __builtin_amdgcn_mfma_f32_16x16x32_bf16(pf, vf, o[d], 0, 0, 0);
      }
    }
  }

  #pragma unroll
  for (int d = 0; d < 8; ++d)
    #pragma unroll
    for (int r = 0; r < 4; ++r) {
      int row = qrow0 + l4 * 4 + r;
      attn_out[(size_t)row * (NHEAD * DKH) + h * DKH + d * 16 + l15] = f2bf(o[d][r] / lsum[r]);
    }
}

// ---------------- host ----------------
extern "C" void kernel_launch(void* const* d_in, const int* in_sizes, int n_in,
                              void* d_out, int out_size, void* d_ws, size_t ws_size,
                              hipStream_t stream) {
  const int*   tokens  = (const int*)d_in[0];
  const float* table   = (const float*)d_in[1];
  const float* wq      = (const float*)d_in[2];
  const float* wk      = (const float*)d_in[3];
  const float* wv      = (const float*)d_in[4];
  const float* wo      = (const float*)d_in[5];
  const float* w_up    = (const float*)d_in[6];
  const float* w_down  = (const float*)d_in[7];
  const float* w_vocab = (const float*)d_in[8];
  float* out = (float*)d_out;

  char* base = (char*)d_ws;
  size_t o = 0;
  auto alloc = [&](size_t bytes) { size_t r = o; o += (bytes + 255) & ~(size_t)255; return r; };
  size_t o_x     = alloc((size_t)SEQ * EMB * 4);
  size_t o_nbf   = alloc((size_t)SEQ * EMB * 2);
  size_t o_qkvw  = alloc((size_t)QKV_N * EMB * 2);
  size_t o_wot   = alloc((size_t)EMB * EMB * 2);
  size_t o_wupt  = alloc((size_t)2 * HIDN * EMB * 2);
  size_t o_wdnt  = alloc((size_t)EMB * HIDN * 2);
  size_t o_qkvf  = alloc((size_t)SEQ * QKV_N * 4);
  size_t o_qbf   = alloc((size_t)NHEAD * SEQ * DKH * 2);
  size_t o_kbf   = alloc((size_t)NKV * SEQ * DKH * 2);
  size_t o_vbf   = alloc((size_t)NKV * SEQ * DKH * 2);
  size_t o_attn  = alloc((size_t)SEQ * EMB * 2);
  size_t o_big   = alloc((size_t)SEQ * 2 * HIDN * 4);   // split-K partials / wvoc_t
  size_t o_hbf   = alloc((size_t)SEQ * HIDN * 2);

  float* x      = (float*)(base + o_x);
  bf16u* n_bf   = (bf16u*)(base + o_nbf);
  bf16u* qkvw_t = (bf16u*)(base + o_qkvw);
  bf16u* wo_t   = (bf16u*)(base + o_wot);
  bf16u* wup_t  = (bf16u*)(base + o_wupt);
  bf16u* wdn_t  = (bf16u*)(base + o_wdnt);
  float* qkv_f  = (float*)(base + o_qkvf);
  bf16u* q_bf   = (bf16u*)(base + o_qbf);
  bf16u* k_bf   = (bf16u*)(base + o_kbf);
  bf16u* v_bf   = (bf16u*)(base + o_vbf);
  bf16u* attn_b = (bf16u*)(base + o_attn);
  float* part   = (float*)(base + o_big);
  bf16u* h_bf   = (bf16u*)(base + o_hbf);
  bf16u* wvoc_t = (bf16u*)(base + o_big);

  embed_kernel<<<SEQ, 256, 0, stream>>>(tokens, table, x);
  rmsnorm_kernel<<<SEQ, 256, 0, stream>>>(x, n_bf);   // layer-0 pre-qkv norm

  for (int l = 0; l < NLAY; ++l) {
    transp_kernel<<<dim3(EMB / 64, EMB / 64), 256, 0, stream>>>(
        wq + (size_t)l * EMB * EMB, qkvw_t, EMB, EMB, 0);
    transp_kernel<<<dim3(512 / 64, EMB / 64), 256, 0, stream>>>(
        wk + (size_t)l * EMB * 512, qkvw_t + (size_t)2048 * EMB, EMB, 512, 0);
    transp_kernel<<<dim3(512 / 64, EMB / 64), 256, 0, stream>>>(
        wv + (size_t)l * EMB * 512, qkvw_t + (size_t)2560 * EMB, EMB, 512, 0);
    transp_kernel<<<dim3(EMB / 64, EMB / 64), 256, 0, stream>>>(
        wo + (size_t)l * EMB * EMB, wo_t, EMB, EMB, 0);
    transp_kernel<<<dim3(2 * HIDN / 64, EMB / 64), 256, 0, stream>>>(
        w_up + (size_t)l * EMB * 2 * HIDN, wup_t, EMB, 2 * HIDN, HIDN);
    transp_kernel<<<dim3(EMB / 64, HIDN / 64), 256, 0, stream>>>(
        w_down + (size_t)l * HIDN * EMB, wdn_t, HIDN, EMB, 0);

    gemm_kernel<2><<<dim3(QKV_N / 128, SEQ / 128), 256, 0, stream>>>(
        n_bf, qkvw_t, qkv_f, SEQ, QKV_N, EMB);

    rope_kernel<<<NHEAD * SEQ * 64 / 256, 256, 0, stream>>>(qkv_f, q_bf, 0);
    rope_kernel<<<NKV * SEQ * 64 / 256, 256, 0, stream>>>(qkv_f, k_bf, 2048);
    vconv_kernel<<<NKV * SEQ * 128 / 256, 256, 0, stream>>>(qkv_f, v_bf);

    attn_kernel<<<dim3(SEQ / 64, NHEAD), 256, 0, stream>>>(q_bf, k_bf, v_bf, attn_b);

    gemm_kernel<1><<<dim3(EMB / 128, SEQ / 128), 256, 0, stream>>>(
        attn_b, wo_t, x, SEQ, EMB, EMB);

    rmsnorm_kernel<<<SEQ, 256, 0, stream>>>(x, n_bf);   // pre-up norm
    gemm256_kernel<3><<<dim3(2 * HIDN / 256, SEQ / 256), 512, 0, stream>>>(
        n_bf, wup_t, h_bf, SEQ, 2 * HIDN, EMB, EMB);
    gemm256_kernel<2><<<dim3(EMB / 256, SEQ / 256, 4), 512, 0, stream>>>(
        h_bf, wdn_t, part, SEQ, EMB, 2048, HIDN);
    // fused: x += sum(partials); n_bf = rmsnorm(x)  (pre-qkv of next layer / final norm)
    reduce4norm_kernel<<<SEQ, 256, 0, stream>>>(x, part, n_bf);
  }

  transp_kernel<<<dim3(NVOC / 64, EMB / 64), 256, 0, stream>>>(w_vocab, wvoc_t, EMB, NVOC, 0);
  gemm256_kernel<2><<<dim3(NVOC / 256, SEQ / 256), 512, 0, stream>>>(
      n_bf, wvoc_t, out, SEQ, NVOC, EMB, EMB);
}

// Round 7
// 2466.550 us; speedup vs baseline: 1.4333x; 1.0116x over previous
//
#include <hip/hip_runtime.h>
#include <cstdint>

typedef unsigned short bf16u;
typedef __attribute__((ext_vector_type(8))) short short8;
typedef __attribute__((ext_vector_type(4))) short short4v;
typedef __attribute__((ext_vector_type(4))) float f32x4;

#define SEQ   2048
#define EMB   2048
#define NHEAD 16
#define NKV   4
#define DKH   128
#define HIDN  8192
#define NVOC  32000
#define NLAY  4
#define WIN   1024
#define QKV_N 3072

__device__ __forceinline__ bf16u f2bf(float f) {
  union { float f; uint32_t u; } v; v.f = f;
  uint32_t r = v.u + 0x7FFFu + ((v.u >> 16) & 1u);
  return (bf16u)(r >> 16);
}

__device__ __forceinline__ void gl2lds16(const void* g, void* l) {
  __builtin_amdgcn_global_load_lds(
      (const __attribute__((address_space(1))) void*)g,
      (__attribute__((address_space(3))) void*)l, 16, 0, 0);
}

// ---------------- embedding ----------------
__global__ __launch_bounds__(256) void embed_kernel(const int* __restrict__ tokens,
                                                    const float* __restrict__ table,
                                                    float* __restrict__ x) {
  int s = blockIdx.x;
  int tok = tokens[s];
  int i0 = threadIdx.x * 8;
  float4 a = {0,0,0,0}, b = {0,0,0,0};
  if (tok != 0) {
    const float* src = table + (size_t)tok * EMB;
    a = *(const float4*)(src + i0);
    b = *(const float4*)(src + i0 + 4);
  }
  *(float4*)(x + (size_t)s * EMB + i0) = a;
  *(float4*)(x + (size_t)s * EMB + i0 + 4) = b;
}

// ---------------- rmsnorm (standalone) ----------------
__global__ __launch_bounds__(256) void rmsnorm_kernel(const float* __restrict__ x,
                                                      bf16u* __restrict__ out) {
  int s = blockIdx.x;
  const float* row = x + (size_t)s * EMB;
  int i0 = threadIdx.x * 8;
  float4 a = *(const float4*)(row + i0);
  float4 b = *(const float4*)(row + i0 + 4);
  float ss = a.x*a.x + a.y*a.y + a.z*a.z + a.w*a.w
           + b.x*b.x + b.y*b.y + b.z*b.z + b.w*b.w;
  #pragma unroll
  for (int off = 1; off < 64; off <<= 1) ss += __shfl_xor(ss, off);
  __shared__ float red[4];
  if ((threadIdx.x & 63) == 0) red[threadIdx.x >> 6] = ss;
  __syncthreads();
  float scale = rsqrtf((red[0] + red[1] + red[2] + red[3]) * (1.0f / EMB) + 1e-5f);
  float v[8] = {a.x, a.y, a.z, a.w, b.x, b.y, b.z, b.w};
  short8 o;
  #pragma unroll
  for (int j = 0; j < 8; ++j) o[j] = (short)f2bf(v[j] * scale);
  *(short8*)(out + (size_t)s * EMB + i0) = o;
}

// ---------------- fused split-K reduce + residual + rmsnorm ----------------
__global__ __launch_bounds__(256) void reduce4norm_kernel(float* __restrict__ x,
                                                          const float* __restrict__ p,
                                                          bf16u* __restrict__ nout) {
  int s = blockIdx.x;
  const size_t MN = (size_t)SEQ * EMB;
  size_t base = (size_t)s * EMB + threadIdx.x * 8;
  float v[8];
  #pragma unroll
  for (int h = 0; h < 2; ++h) {
    size_t i = base + h * 4;
    float4 a  = *(const float4*)(x + i);
    float4 b0 = *(const float4*)(p + i);
    float4 b1 = *(const float4*)(p + i + MN);
    float4 b2 = *(const float4*)(p + i + 2 * MN);
    float4 b3 = *(const float4*)(p + i + 3 * MN);
    v[h*4+0] = a.x + b0.x + b1.x + b2.x + b3.x;
    v[h*4+1] = a.y + b0.y + b1.y + b2.y + b3.y;
    v[h*4+2] = a.z + b0.z + b1.z + b2.z + b3.z;
    v[h*4+3] = a.w + b0.w + b1.w + b2.w + b3.w;
    *(float4*)(x + i) = make_float4(v[h*4+0], v[h*4+1], v[h*4+2], v[h*4+3]);
  }
  float ss = 0.0f;
  #pragma unroll
  for (int j = 0; j < 8; ++j) ss += v[j] * v[j];
  #pragma unroll
  for (int off = 1; off < 64; off <<= 1) ss += __shfl_xor(ss, off);
  __shared__ float red[4];
  if ((threadIdx.x & 63) == 0) red[threadIdx.x >> 6] = ss;
  __syncthreads();
  float scale = rsqrtf((red[0] + red[1] + red[2] + red[3]) * (1.0f / EMB) + 1e-5f);
  short8 o;
  #pragma unroll
  for (int j = 0; j < 8; ++j) o[j] = (short)f2bf(v[j] * scale);
  *(short8*)(nout + base) = o;
}

// ---------------- transpose + convert, 64x64 tiles ----------------
__global__ __launch_bounds__(256) void transp_kernel(const float* __restrict__ in,
                                                     bf16u* __restrict__ out,
                                                     int R, int C, int pairhalf) {
  __shared__ float tile[64][65];
  int c0 = blockIdx.x * 64, r0 = blockIdx.y * 64;
  int tx = threadIdx.x & 15, ty = threadIdx.x >> 4;
  #pragma unroll
  for (int i = 0; i < 4; ++i) {
    int r = ty + i * 16;
    float4 v = *(const float4*)(in + (size_t)(r0 + r) * C + c0 + tx * 4);
    tile[tx * 4 + 0][r] = v.x;
    tile[tx * 4 + 1][r] = v.y;
    tile[tx * 4 + 2][r] = v.z;
    tile[tx * 4 + 3][r] = v.w;
  }
  __syncthreads();
  int rx = threadIdx.x & 15, cy = threadIdx.x >> 4;
  #pragma unroll
  for (int i = 0; i < 4; ++i) {
    int c = c0 + cy + i * 16;
    int n = pairhalf ? (c < pairhalf ? 2 * c : 2 * (c - pairhalf) + 1) : c;
    short4v o;
    #pragma unroll
    for (int j = 0; j < 4; ++j) o[j] = (short)f2bf(tile[cy + i * 16][rx * 4 + j]);
    *(short4v*)(out + (size_t)n * R + r0 + rx * 4) = o;
  }
}

// ---------------- RoPE ----------------
__global__ __launch_bounds__(256) void rope_kernel(const float* __restrict__ qkv,
                                                   bf16u* __restrict__ out, int col0) {
  int idx = blockIdx.x * 256 + threadIdx.x;
  int d = idx & 63;
  int s = (idx >> 6) & (SEQ - 1);
  int h = idx >> 17;
  const float* row = qkv + (size_t)s * QKV_N + col0 + h * DKH;
  float ang = (float)s * __powf(10000.0f, -(float)d * (1.0f / 64.0f));
  float si, c;
  sincosf(ang, &si, &c);
  float f0 = row[d], f1 = row[d + 64];
  bf16u* orow = out + ((size_t)h * SEQ + s) * DKH;
  orow[d]      = f2bf(c * f0 - si * f1);
  orow[d + 64] = f2bf(c * f1 + si * f0);
}

__global__ __launch_bounds__(256) void vconv_kernel(const float* __restrict__ qkv,
                                                    bf16u* __restrict__ vout) {
  int idx = blockIdx.x * 256 + threadIdx.x;
  int d = idx & 127;
  int kv = (idx >> 7) & 3;
  int s = idx >> 9;
  vout[((size_t)kv * SEQ + s) * DKH + d] = f2bf(qkv[(size_t)s * QKV_N + 2560 + kv * DKH + d]);
}

// ================= 128x128 2-phase GEMM =================
template <int MODE>
__global__ __launch_bounds__(256) void gemm_kernel(const bf16u* __restrict__ A,
                                                   const bf16u* __restrict__ Bt,
                                                   void* __restrict__ C,
                                                   int M, int N, int K) {
  __shared__ __align__(16) char lds[2][2][8192];

  int nx = gridDim.x, ny = gridDim.y;
  int nwg = nx * ny;
  int orig = blockIdx.y * nx + blockIdx.x;
  int q = nwg >> 3, r = nwg & 7;
  int xcd = orig & 7, loc = orig >> 3;
  int id = (xcd < r ? xcd * (q + 1) : r * (q + 1) + (xcd - r) * q) + loc;
  int bx = id / ny, by = id - bx * ny;
  int n0 = bx * 128, m0 = by * 128;

  int t = threadIdx.x;
  int w = t >> 6, l = t & 63;
  int wm = (w >> 1) * 64, wn = (w & 1) * 64;
  int l15 = l & 15, l4 = l >> 4;

  int srow = w * 16 + (l >> 2);
  int scol = (l & 3) * 8;

  f32x4 acc[4][4] = {};

  auto stage = [&](int buf, int k0) {
    #pragma unroll
    for (int i = 0; i < 2; ++i) {
      gl2lds16(A  + (size_t)(m0 + i * 64 + srow) * K + k0 + scol,
               &lds[buf][0][i * 4096 + w * 1024]);
      gl2lds16(Bt + (size_t)(n0 + i * 64 + srow) * K + k0 + scol,
               &lds[buf][1][i * 4096 + w * 1024]);
    }
  };

  auto compute = [&](int buf) {
    short8 af[4], bfr[4];
    #pragma unroll
    for (int i = 0; i < 4; ++i) {
      af[i]  = *(const short8*)(&lds[buf][0][((wm + i * 16 + l15) * 32 + l4 * 8) * 2]);
      bfr[i] = *(const short8*)(&lds[buf][1][((wn + i * 16 + l15) * 32 + l4 * 8) * 2]);
    }
    #pragma unroll
    for (int i = 0; i < 4; ++i)
      #pragma unroll
      for (int j = 0; j < 4; ++j)
        acc[i][j] = __builtin_amdgcn_mfma_f32_16x16x32_bf16(af[i], bfr[j], acc[i][j], 0, 0, 0);
  };

  int nt = K >> 5;
  int cur = 0;
  stage(0, 0);
  __syncthreads();
  for (int tt = 0; tt < nt; ++tt) {
    if (tt + 1 < nt) stage(cur ^ 1, (tt + 1) * 32);
    compute(cur);
    __syncthreads();
    cur ^= 1;
  }

  #pragma unroll
  for (int i = 0; i < 4; ++i)
    #pragma unroll
    for (int j = 0; j < 4; ++j) {
      int col = n0 + wn + j * 16 + l15;
      #pragma unroll
      for (int rr = 0; rr < 4; ++rr) {
        int row = m0 + wm + i * 16 + l4 * 4 + rr;
        float v = acc[i][j][rr];
        if (MODE == 0) {
          ((bf16u*)C)[(size_t)row * N + col] = f2bf(v);
        } else if (MODE == 1) {
          float* p = (float*)C + (size_t)row * N + col;
          *p += v;
        } else {
          ((float*)C)[(size_t)row * N + col] = v;
        }
      }
    }
}

// ================= 256x256 8-phase GEMM (T1+T2+T3+T4+T5) =================
__device__ __forceinline__ void stage_half(const bf16u* __restrict__ p, int ld,
                                           int row0, int k0, char* slotBase, int t) {
  int r  = t >> 3, c8 = t & 7;
  int cs = (c8 ^ (r & 7)) << 3;
  gl2lds16(p + (size_t)(row0 + r) * ld + k0 + cs, slotBase + t * 16);
  gl2lds16(p + (size_t)(row0 + 64 + r) * ld + k0 + cs, slotBase + 8192 + t * 16);
}

template<int KK>
__device__ __forceinline__ short8 read_frag(const char* slot, int row, int l4) {
  int kc = KK * 4 + l4;
  return *(const short8*)(slot + row * 128 + ((kc ^ (row & 7)) << 4));
}

template<int NH>
__device__ __forceinline__ void mfma_quad(f32x4 (&acc)[8][4], const short8 (&a)[8],
                                          short8 b0, short8 b1) {
  __builtin_amdgcn_s_setprio(1);
  #pragma unroll
  for (int mi = 0; mi < 8; ++mi) {
    acc[mi][NH * 2]     = __builtin_amdgcn_mfma_f32_16x16x32_bf16(a[mi], b0, acc[mi][NH * 2], 0, 0, 0);
    acc[mi][NH * 2 + 1] = __builtin_amdgcn_mfma_f32_16x16x32_bf16(a[mi], b1, acc[mi][NH * 2 + 1], 0, 0, 0);
  }
  __builtin_amdgcn_s_setprio(0);
}

template <int MODE>
__global__ __launch_bounds__(512) void gemm256_kernel(const bf16u* __restrict__ A,
                                                      const bf16u* __restrict__ Bt,
                                                      void* __restrict__ C,
                                                      int M, int N, int K, int ldk) {
  __shared__ __align__(16) char lds[131072];

  int koff = blockIdx.z * K;
  A  += koff;
  Bt += koff;
  float* Cz = (float*)C + (size_t)blockIdx.z * M * N;

  int nx = gridDim.x, ny = gridDim.y;
  int nwg = nx * ny;
  int orig = blockIdx.y * nx + blockIdx.x;
  int q8 = nwg >> 3, r8 = nwg & 7;
  int xcd = orig & 7, loc = orig >> 3;
  int id = (xcd < r8 ? xcd * (q8 + 1) : r8 * (q8 + 1) + (xcd - r8) * q8) + loc;
  int bx = id / ny, by = id - bx * ny;
  int n0 = bx * 256, m0 = by * 256;

  int t = threadIdx.x;
  int wid = t >> 6, lane = t & 63;
  int wr = wid >> 2, wc = wid & 3, bh = wc >> 1;
  int l15 = lane & 15, l4 = lane >> 4;

  char* AS0 = lds;              char* AS1 = lds + 16384;
  char* AS2 = lds + 32768;      char* AS3 = lds + 49152;
  char* BS0 = lds + 65536;      char* BS1 = lds + 81920;
  char* BS2 = lds + 98304;      char* BS3 = lds + 114688;

  const char* ASe = lds + wr * 16384;
  const char* ASo = ASe + 32768;
  const char* BSe = lds + 65536 + bh * 16384;
  const char* BSo = BSe + 32768;

  int brow = (wc & 1) * 64;

  f32x4 acc[8][4] = {};
  short8 a[8];
  short8 b0, b1;

  int NT = K >> 6;
  int NI = NT >> 1;

  stage_half(A,  ldk, m0,       0,  AS0, t);
  stage_half(A,  ldk, m0 + 128, 0,  AS1, t);
  stage_half(Bt, ldk, n0,       0,  BS0, t);
  stage_half(Bt, ldk, n0 + 128, 0,  BS1, t);
  stage_half(A,  ldk, m0,       64, AS2, t);
  asm volatile("s_waitcnt vmcnt(2)" ::: "memory");
  __builtin_amdgcn_s_barrier();
  __builtin_amdgcn_sched_barrier(0);

  for (int I = 0; I < NI; ++I) {
    int t0k = I * 128;
    int t1k = t0k + 64;
    bool notlast = (I + 1 < NI);

    #pragma unroll
    for (int mi = 0; mi < 8; ++mi) a[mi] = read_frag<0>(ASe, mi * 16 + l15, l4);
    b0 = read_frag<0>(BSe, brow + l15, l4);
    b1 = read_frag<0>(BSe, brow + 16 + l15, l4);
    stage_half(A, ldk, m0 + 128, t1k, AS3, t);
    __builtin_amdgcn_s_barrier();
    mfma_quad<0>(acc, a, b0, b1);
    __builtin_amdgcn_s_barrier();

    b0 = read_frag<0>(BSe, brow + 32 + l15, l4);
    b1 = read_frag<0>(BSe, brow + 48 + l15, l4);
    stage_half(Bt, ldk, n0, t1k, BS2, t);
    __builtin_amdgcn_s_barrier();
    mfma_quad<1>(acc, a, b0, b1);
    __builtin_amdgcn_s_barrier();

    #pragma unroll
    for (int mi = 0; mi < 8; ++mi) a[mi] = read_frag<1>(ASe, mi * 16 + l15, l4);
    b0 = read_frag<1>(BSe, brow + l15, l4);
    b1 = read_frag<1>(BSe, brow + 16 + l15, l4);
    stage_half(Bt, ldk, n0 + 128, t1k, BS3, t);
    __builtin_amdgcn_s_barrier();
    mfma_quad<0>(acc, a, b0, b1);
    __builtin_amdgcn_s_barrier();

    b0 = read_frag<1>(BSe, brow + 32 + l15, l4);
    b1 = read_frag<1>(BSe, brow + 48 + l15, l4);
    if (notlast) stage_half(A, ldk, m0, t0k + 128, AS0, t);
    if (notlast) { asm volatile("s_waitcnt vmcnt(2)" ::: "memory"); }
    else         { asm volatile("s_waitcnt vmcnt(0)" ::: "memory"); }
    __builtin_amdgcn_s_barrier();
    __builtin_amdgcn_sched_barrier(0);
    mfma_quad<1>(acc, a, b0, b1);
    __builtin_amdgcn_s_barrier();

    #pragma unroll
    for (int mi = 0; mi < 8; ++mi) a[mi] = read_frag<0>(ASo, mi * 16 + l15, l4);
    b0 = read_frag<0>(BSo, brow + l15, l4);
    b1 = read_frag<0>(BSo, brow + 16 + l15, l4);
    if (notlast) stage_half(A, ldk, m0 + 128, t0k + 128, AS1, t);
    __builtin_amdgcn_s_barrier();
    mfma_quad<0>(acc, a, b0, b1);
    __builtin_amdgcn_s_barrier();

    b0 = read_frag<0>(BSo, brow + 32 + l15, l4);
    b1 = read_frag<0>(BSo, brow + 48 + l15, l4);
    if (notlast) stage_half(Bt, ldk, n0, t0k + 128, BS0, t);
    __builtin_amdgcn_s_barrier();
    mfma_quad<1>(acc, a, b0, b1);
    __builtin_amdgcn_s_barrier();

    #pragma unroll
    for (int mi = 0; mi < 8; ++mi) a[mi] = read_frag<1>(ASo, mi * 16 + l15, l4);
    b0 = read_frag<1>(BSo, brow + l15, l4);
    b1 = read_frag<1>(BSo, brow + 16 + l15, l4);
    if (notlast) stage_half(Bt, ldk, n0 + 128, t0k + 128, BS1, t);
    __builtin_amdgcn_s_barrier();
    mfma_quad<0>(acc, a, b0, b1);
    __builtin_amdgcn_s_barrier();

    b0 = read_frag<1>(BSo, brow + 32 + l15, l4);
    b1 = read_frag<1>(BSo, brow + 48 + l15, l4);
    if (notlast) {
      stage_half(A, ldk, m0, t0k + 192, AS2, t);
      asm volatile("s_waitcnt vmcnt(2)" ::: "memory");
    }
    __builtin_amdgcn_s_barrier();
    __builtin_amdgcn_sched_barrier(0);
    mfma_quad<1>(acc, a, b0, b1);
    __builtin_amdgcn_s_barrier();
  }

  #pragma unroll
  for (int mi = 0; mi < 8; ++mi)
    #pragma unroll
    for (int ni = 0; ni < 4; ++ni) {
      int col = n0 + wc * 64 + ni * 16 + l15;
      #pragma unroll
      for (int rr = 0; rr < 4; ++rr) {
        int row = m0 + wr * 128 + mi * 16 + l4 * 4 + rr;
        float v = acc[mi][ni][rr];
        if (MODE == 3) {
          float pv = __shfl_xor(v, 1);
          if ((l15 & 1) == 0) {
            float hval = pv * (v / (1.0f + __expf(-v)));
            ((bf16u*)C)[(size_t)row * HIDN + (col >> 1)] = f2bf(hval);
          }
        } else if (MODE == 2) {
          Cz[(size_t)row * N + col] = v;
        } else if (MODE == 1) {
          float* p = (float*)C + (size_t)row * N + col;
          *p += v;
        } else {
          ((bf16u*)C)[(size_t)row * N + col] = f2bf(v);
        }
      }
    }
}

// ---------------- sliding-window flash attention (QBLK=128, 8 waves) ----------------
__global__ __launch_bounds__(512) void attn_kernel(const bf16u* __restrict__ q_bf,
                                                   const bf16u* __restrict__ k_bf,
                                                   const bf16u* __restrict__ v_bf,
                                                   bf16u* __restrict__ attn_out) {
  int h = blockIdx.y;
  int q0 = blockIdx.x * 128;
  int kvh = h >> 2;
  const bf16u* Kp = k_bf + (size_t)kvh * SEQ * DKH;
  const bf16u* Vp = v_bf + (size_t)kvh * SEQ * DKH;

  __shared__ __align__(16) char  Klds[64 * 128 * 2];   // swizzled [key][dim]
  __shared__ __align__(16) bf16u Vlds[128][72];        // [dim][key]
  __shared__ __align__(16) bf16u Plds[8][16][72];      // per-wave [qrow][key]

  int t = threadIdx.x, wave = t >> 6, lane = t & 63;
  int l15 = lane & 15, l4 = lane >> 4;
  int qrow0 = q0 + wave * 16;

  short8 qf[4];
  #pragma unroll
  for (int ks = 0; ks < 4; ++ks)
    qf[ks] = *(const short8*)(q_bf + ((size_t)h * SEQ + qrow0 + l15) * DKH + ks * 32 + l4 * 8);

  f32x4 o[8] = {};
  float m[4], lsum[4];
  #pragma unroll
  for (int r = 0; r < 4; ++r) { m[r] = -INFINITY; lsum[r] = 0.0f; }

  // conflict-free V-transpose mapping: key spans the wave (banks 0..31, 2-way)
  int vkey = t & 63, vd0 = (t >> 6) * 16;

  int jstart = q0 >= WIN ? ((q0 - (WIN - 1)) & ~63) : 0;

  for (int j0 = jstart; j0 < q0 + 128; j0 += 64) {
    __syncthreads();
    // stage K (64x128, XOR-swizzled rows), 512 threads
    #pragma unroll
    for (int i = 0; i < 2; ++i) {
      int c = t + i * 512;
      int key = c >> 4, cc = c & 15;
      int off = key * 256 + cc * 16; off ^= (key & 7) << 4;
      *(short8*)(Klds + off) = *(const short8*)(Kp + (size_t)(j0 + key) * DKH + cc * 8);
    }
    // stage V transposed (scalar stores, all 32 banks)
    {
      const bf16u* src = Vp + (size_t)(j0 + vkey) * DKH + vd0;
      short8 v0 = *(const short8*)(src);
      short8 v1 = *(const short8*)(src + 8);
      #pragma unroll
      for (int i = 0; i < 8; ++i) Vlds[vd0 + i][vkey] = (bf16u)(unsigned short)v0[i];
      #pragma unroll
      for (int i = 0; i < 8; ++i) Vlds[vd0 + 8 + i][vkey] = (bf16u)(unsigned short)v1[i];
    }
    __syncthreads();

    // S = Q K^T (four 16-key tiles)
    f32x4 sacc[4] = {};
    #pragma unroll
    for (int nt = 0; nt < 4; ++nt) {
      int key = nt * 16 + l15;
      #pragma unroll
      for (int ks = 0; ks < 4; ++ks) {
        int off = key * 256 + ks * 64 + l4 * 16; off ^= (key & 7) << 4;
        short8 kf = *(short8*)(Klds + off);
        sacc[nt] = __builtin_amdgcn_mfma_f32_16x16x32_bf16(qf[ks], kf, sacc[nt], 0, 0, 0);
      }
    }

    // mask + scale
    float sv[4][4];
    #pragma unroll
    for (int nt = 0; nt < 4; ++nt) {
      int jk = j0 + nt * 16 + l15;
      #pragma unroll
      for (int r = 0; r < 4; ++r) {
        int iq = qrow0 + l4 * 4 + r;
        float s = sacc[nt][r] * 0.08838834764831845f;
        bool valid = (jk <= iq) && (iq - jk < WIN);
        sv[nt][r] = valid ? s : -1e9f;
      }
    }

    float mxr[4];
    #pragma unroll
    for (int r = 0; r < 4; ++r) {
      float mx = fmaxf(fmaxf(sv[0][r], sv[1][r]), fmaxf(sv[2][r], sv[3][r]));
      #pragma unroll
      for (int off = 1; off < 16; off <<= 1) mx = fmaxf(mx, __shfl_xor(mx, off));
      mxr[r] = mx;
    }

    bool grow = (mxr[0] > m[0] + 8.0f) || (mxr[1] > m[1] + 8.0f) ||
                (mxr[2] > m[2] + 8.0f) || (mxr[3] > m[3] + 8.0f);
    if (__any(grow)) {
      #pragma unroll
      for (int r = 0; r < 4; ++r) {
        float mn = fmaxf(m[r], mxr[r]);
        float alpha = __expf(m[r] - mn);
        m[r] = mn;
        lsum[r] *= alpha;
        #pragma unroll
        for (int d = 0; d < 8; ++d) o[d][r] *= alpha;
      }
    }

    float p[4][4];
    #pragma unroll
    for (int r = 0; r < 4; ++r) {
      float ps = 0.0f;
      #pragma unroll
      for (int nt = 0; nt < 4; ++nt) { p[nt][r] = __expf(sv[nt][r] - m[r]); ps += p[nt][r]; }
      #pragma unroll
      for (int off = 1; off < 16; off <<= 1) ps += __shfl_xor(ps, off);
      lsum[r] += ps;
    }

    #pragma unroll
    for (int nt = 0; nt < 4; ++nt)
      #pragma unroll
      for (int r = 0; r < 4; ++r)
        Plds[wave][l4 * 4 + r][nt * 16 + l15] = f2bf(p[nt][r]);

    #pragma unroll
    for (int kk = 0; kk < 2; ++kk) {
      short8 pf = *(short8*)(&Plds[wave][l15][kk * 32 + l4 * 8]);
      #pragma unroll
      for (int d = 0; d < 8; ++d) {
        short8 vf = *(short8*)(&Vlds[d * 16 + l15][kk * 32 + l4 * 8]);
        o[d] = __builtin_amdgcn_mfma_f32_16x16x32_bf16(pf, vf, o[d], 0, 0, 0);
      }
    }
  }

  #pragma unroll
  for (int d = 0; d < 8; ++d)
    #pragma unroll
    for (int r = 0; r < 4; ++r) {
      int row = qrow0 + l4 * 4 + r;
      attn_out[(size_t)row * (NHEAD * DKH) + h * DKH + d * 16 + l15] = f2bf(o[d][r] / lsum[r]);
    }
}

// ---------------- host ----------------
extern "C" void kernel_launch(void* const* d_in, const int* in_sizes, int n_in,
                              void* d_out, int out_size, void* d_ws, size_t ws_size,
                              hipStream_t stream) {
  const int*   tokens  = (const int*)d_in[0];
  const float* table   = (const float*)d_in[1];
  const float* wq      = (const float*)d_in[2];
  const float* wk      = (const float*)d_in[3];
  const float* wv      = (const float*)d_in[4];
  const float* wo      = (const float*)d_in[5];
  const float* w_up    = (const float*)d_in[6];
  const float* w_down  = (const float*)d_in[7];
  const float* w_vocab = (const float*)d_in[8];
  float* out = (float*)d_out;

  char* base = (char*)d_ws;
  size_t o = 0;
  auto alloc = [&](size_t bytes) { size_t r = o; o += (bytes + 255) & ~(size_t)255; return r; };
  size_t o_x     = alloc((size_t)SEQ * EMB * 4);
  size_t o_nbf   = alloc((size_t)SEQ * EMB * 2);
  size_t o_qkvw  = alloc((size_t)QKV_N * EMB * 2);
  size_t o_wot   = alloc((size_t)EMB * EMB * 2);
  size_t o_wupt  = alloc((size_t)2 * HIDN * EMB * 2);
  size_t o_wdnt  = alloc((size_t)EMB * HIDN * 2);
  size_t o_qkvf  = alloc((size_t)SEQ * QKV_N * 4);
  size_t o_qbf   = alloc((size_t)NHEAD * SEQ * DKH * 2);
  size_t o_kbf   = alloc((size_t)NKV * SEQ * DKH * 2);
  size_t o_vbf   = alloc((size_t)NKV * SEQ * DKH * 2);
  size_t o_attn  = alloc((size_t)SEQ * EMB * 2);
  size_t o_big   = alloc((size_t)SEQ * 2 * HIDN * 4);
  size_t o_hbf   = alloc((size_t)SEQ * HIDN * 2);

  float* x      = (float*)(base + o_x);
  bf16u* n_bf   = (bf16u*)(base + o_nbf);
  bf16u* qkvw_t = (bf16u*)(base + o_qkvw);
  bf16u* wo_t   = (bf16u*)(base + o_wot);
  bf16u* wup_t  = (bf16u*)(base + o_wupt);
  bf16u* wdn_t  = (bf16u*)(base + o_wdnt);
  float* qkv_f  = (float*)(base + o_qkvf);
  bf16u* q_bf   = (bf16u*)(base + o_qbf);
  bf16u* k_bf   = (bf16u*)(base + o_kbf);
  bf16u* v_bf   = (bf16u*)(base + o_vbf);
  bf16u* attn_b = (bf16u*)(base + o_attn);
  float* part   = (float*)(base + o_big);
  bf16u* h_bf   = (bf16u*)(base + o_hbf);
  bf16u* wvoc_t = (bf16u*)(base + o_big);

  embed_kernel<<<SEQ, 256, 0, stream>>>(tokens, table, x);
  rmsnorm_kernel<<<SEQ, 256, 0, stream>>>(x, n_bf);

  for (int l = 0; l < NLAY; ++l) {
    transp_kernel<<<dim3(EMB / 64, EMB / 64), 256, 0, stream>>>(
        wq + (size_t)l * EMB * EMB, qkvw_t, EMB, EMB, 0);
    transp_kernel<<<dim3(512 / 64, EMB / 64), 256, 0, stream>>>(
        wk + (size_t)l * EMB * 512, qkvw_t + (size_t)2048 * EMB, EMB, 512, 0);
    transp_kernel<<<dim3(512 / 64, EMB / 64), 256, 0, stream>>>(
        wv + (size_t)l * EMB * 512, qkvw_t + (size_t)2560 * EMB, EMB, 512, 0);
    transp_kernel<<<dim3(EMB / 64, EMB / 64), 256, 0, stream>>>(
        wo + (size_t)l * EMB * EMB, wo_t, EMB, EMB, 0);
    transp_kernel<<<dim3(2 * HIDN / 64, EMB / 64), 256, 0, stream>>>(
        w_up + (size_t)l * EMB * 2 * HIDN, wup_t, EMB, 2 * HIDN, HIDN);
    transp_kernel<<<dim3(EMB / 64, HIDN / 64), 256, 0, stream>>>(
        w_down + (size_t)l * HIDN * EMB, wdn_t, HIDN, EMB, 0);

    gemm_kernel<2><<<dim3(QKV_N / 128, SEQ / 128), 256, 0, stream>>>(
        n_bf, qkvw_t, qkv_f, SEQ, QKV_N, EMB);

    rope_kernel<<<NHEAD * SEQ * 64 / 256, 256, 0, stream>>>(qkv_f, q_bf, 0);
    rope_kernel<<<NKV * SEQ * 64 / 256, 256, 0, stream>>>(qkv_f, k_bf, 2048);
    vconv_kernel<<<NKV * SEQ * 128 / 256, 256, 0, stream>>>(qkv_f, v_bf);

    attn_kernel<<<dim3(SEQ / 128, NHEAD), 512, 0, stream>>>(q_bf, k_bf, v_bf, attn_b);

    gemm_kernel<1><<<dim3(EMB / 128, SEQ / 128), 256, 0, stream>>>(
        attn_b, wo_t, x, SEQ, EMB, EMB);

    rmsnorm_kernel<<<SEQ, 256, 0, stream>>>(x, n_bf);
    gemm256_kernel<3><<<dim3(2 * HIDN / 256, SEQ / 256), 512, 0, stream>>>(
        n_bf, wup_t, h_bf, SEQ, 2 * HIDN, EMB, EMB);
    gemm256_kernel<2><<<dim3(EMB / 256, SEQ / 256, 4), 512, 0, stream>>>(
        h_bf, wdn_t, part, SEQ, EMB, 2048, HIDN);
    reduce4norm_kernel<<<SEQ, 256, 0, stream>>>(x, part, n_bf);
  }

  transp_kernel<<<dim3(NVOC / 64, EMB / 64), 256, 0, stream>>>(w_vocab, wvoc_t, EMB, NVOC, 0);
  gemm256_kernel<2><<<dim3(NVOC / 256, SEQ / 256), 512, 0, stream>>>(
      n_bf, wvoc_t, out, SEQ, NVOC, EMB, EMB);
}

// Round 8
// 2349.481 us; speedup vs baseline: 1.5047x; 1.0498x over previous
//
#include <hip/hip_runtime.h>
#include <cstdint>

typedef unsigned short bf16u;
typedef __attribute__((ext_vector_type(8))) short short8;
typedef __attribute__((ext_vector_type(4))) short short4v;
typedef __attribute__((ext_vector_type(4))) float f32x4;

#define SEQ   2048
#define EMB   2048
#define NHEAD 16
#define NKV   4
#define DKH   128
#define HIDN  8192
#define NVOC  32000
#define NLAY  4
#define WIN   1024
#define QKV_N 3072

__device__ __forceinline__ bf16u f2bf(float f) {
  union { float f; uint32_t u; } v; v.f = f;
  uint32_t r = v.u + 0x7FFFu + ((v.u >> 16) & 1u);
  return (bf16u)(r >> 16);
}
__device__ __forceinline__ float bf2f(bf16u b) {
  union { uint32_t u; float f; } v; v.u = ((uint32_t)b) << 16;
  return v.f;
}

__device__ __forceinline__ void gl2lds16(const void* g, void* l) {
  __builtin_amdgcn_global_load_lds(
      (const __attribute__((address_space(1))) void*)g,
      (__attribute__((address_space(3))) void*)l, 16, 0, 0);
}

// ---------------- embedding ----------------
__global__ __launch_bounds__(256) void embed_kernel(const int* __restrict__ tokens,
                                                    const float* __restrict__ table,
                                                    float* __restrict__ x) {
  int s = blockIdx.x;
  int tok = tokens[s];
  int i0 = threadIdx.x * 8;
  float4 a = {0,0,0,0}, b = {0,0,0,0};
  if (tok != 0) {
    const float* src = table + (size_t)tok * EMB;
    a = *(const float4*)(src + i0);
    b = *(const float4*)(src + i0 + 4);
  }
  *(float4*)(x + (size_t)s * EMB + i0) = a;
  *(float4*)(x + (size_t)s * EMB + i0 + 4) = b;
}

// ---------------- rmsnorm (standalone) ----------------
__global__ __launch_bounds__(256) void rmsnorm_kernel(const float* __restrict__ x,
                                                      bf16u* __restrict__ out) {
  int s = blockIdx.x;
  const float* row = x + (size_t)s * EMB;
  int i0 = threadIdx.x * 8;
  float4 a = *(const float4*)(row + i0);
  float4 b = *(const float4*)(row + i0 + 4);
  float ss = a.x*a.x + a.y*a.y + a.z*a.z + a.w*a.w
           + b.x*b.x + b.y*b.y + b.z*b.z + b.w*b.w;
  #pragma unroll
  for (int off = 1; off < 64; off <<= 1) ss += __shfl_xor(ss, off);
  __shared__ float red[4];
  if ((threadIdx.x & 63) == 0) red[threadIdx.x >> 6] = ss;
  __syncthreads();
  float scale = rsqrtf((red[0] + red[1] + red[2] + red[3]) * (1.0f / EMB) + 1e-5f);
  float v[8] = {a.x, a.y, a.z, a.w, b.x, b.y, b.z, b.w};
  short8 o;
  #pragma unroll
  for (int j = 0; j < 8; ++j) o[j] = (short)f2bf(v[j] * scale);
  *(short8*)(out + (size_t)s * EMB + i0) = o;
}

// ---------------- fused split-K reduce + residual + rmsnorm ----------------
__global__ __launch_bounds__(256) void reduce4norm_kernel(float* __restrict__ x,
                                                          const float* __restrict__ p,
                                                          bf16u* __restrict__ nout) {
  int s = blockIdx.x;
  const size_t MN = (size_t)SEQ * EMB;
  size_t base = (size_t)s * EMB + threadIdx.x * 8;
  float v[8];
  #pragma unroll
  for (int h = 0; h < 2; ++h) {
    size_t i = base + h * 4;
    float4 a  = *(const float4*)(x + i);
    float4 b0 = *(const float4*)(p + i);
    float4 b1 = *(const float4*)(p + i + MN);
    float4 b2 = *(const float4*)(p + i + 2 * MN);
    float4 b3 = *(const float4*)(p + i + 3 * MN);
    v[h*4+0] = a.x + b0.x + b1.x + b2.x + b3.x;
    v[h*4+1] = a.y + b0.y + b1.y + b2.y + b3.y;
    v[h*4+2] = a.z + b0.z + b1.z + b2.z + b3.z;
    v[h*4+3] = a.w + b0.w + b1.w + b2.w + b3.w;
    *(float4*)(x + i) = make_float4(v[h*4+0], v[h*4+1], v[h*4+2], v[h*4+3]);
  }
  float ss = 0.0f;
  #pragma unroll
  for (int j = 0; j < 8; ++j) ss += v[j] * v[j];
  #pragma unroll
  for (int off = 1; off < 64; off <<= 1) ss += __shfl_xor(ss, off);
  __shared__ float red[4];
  if ((threadIdx.x & 63) == 0) red[threadIdx.x >> 6] = ss;
  __syncthreads();
  float scale = rsqrtf((red[0] + red[1] + red[2] + red[3]) * (1.0f / EMB) + 1e-5f);
  short8 o;
  #pragma unroll
  for (int j = 0; j < 8; ++j) o[j] = (short)f2bf(v[j] * scale);
  *(short8*)(nout + base) = o;
}

// ---------------- batched transpose + convert, 64x64 tiles, z = layer ----------------
// in[z][R][C] f32 -> out[z*ostride + n(c)*R + r] bf16
__global__ __launch_bounds__(256) void transp_kernel(const float* __restrict__ in,
                                                     bf16u* __restrict__ out,
                                                     int R, int C, int pairhalf,
                                                     size_t ostride) {
  __shared__ float tile[64][65];
  in  += (size_t)blockIdx.z * R * C;
  out += (size_t)blockIdx.z * ostride;
  int c0 = blockIdx.x * 64, r0 = blockIdx.y * 64;
  int tx = threadIdx.x & 15, ty = threadIdx.x >> 4;
  #pragma unroll
  for (int i = 0; i < 4; ++i) {
    int r = ty + i * 16;
    float4 v = *(const float4*)(in + (size_t)(r0 + r) * C + c0 + tx * 4);
    tile[tx * 4 + 0][r] = v.x;
    tile[tx * 4 + 1][r] = v.y;
    tile[tx * 4 + 2][r] = v.z;
    tile[tx * 4 + 3][r] = v.w;
  }
  __syncthreads();
  int rx = threadIdx.x & 15, cy = threadIdx.x >> 4;
  #pragma unroll
  for (int i = 0; i < 4; ++i) {
    int c = c0 + cy + i * 16;
    int n = pairhalf ? (c < pairhalf ? 2 * c : 2 * (c - pairhalf) + 1) : c;
    short4v o;
    #pragma unroll
    for (int j = 0; j < 4; ++j) o[j] = (short)f2bf(tile[cy + i * 16][rx * 4 + j]);
    *(short4v*)(out + (size_t)n * R + r0 + rx * 4) = o;
  }
}

// ---------------- fused RoPE for q+k (reads bf16 qkv), v read in-place by attn ----------------
__global__ __launch_bounds__(256) void rope_kernel(const bf16u* __restrict__ qkv,
                                                   bf16u* __restrict__ q_bf,
                                                   bf16u* __restrict__ k_bf) {
  int idx = blockIdx.x * 256 + threadIdx.x;     // (NHEAD+NKV)*SEQ*64 items
  int d = idx & 63;
  int s = (idx >> 6) & (SEQ - 1);
  int h = idx >> 17;                            // 0..19
  int col0 = (h < NHEAD) ? h * DKH : 2048 + (h - NHEAD) * DKH;
  const bf16u* row = qkv + (size_t)s * QKV_N + col0;
  float ang = (float)s * __powf(10000.0f, -(float)d * (1.0f / 64.0f));
  float si, c;
  sincosf(ang, &si, &c);
  float f0 = bf2f(row[d]), f1 = bf2f(row[d + 64]);
  bf16u* orow = (h < NHEAD) ? q_bf + ((size_t)h * SEQ + s) * DKH
                            : k_bf + ((size_t)(h - NHEAD) * SEQ + s) * DKH;
  orow[d]      = f2bf(c * f0 - si * f1);
  orow[d + 64] = f2bf(c * f1 + si * f0);
}

// ================= 128x128 2-phase GEMM =================
template <int MODE>
__global__ __launch_bounds__(256) void gemm_kernel(const bf16u* __restrict__ A,
                                                   const bf16u* __restrict__ Bt,
                                                   void* __restrict__ C,
                                                   int M, int N, int K) {
  __shared__ __align__(16) char lds[2][2][8192];

  int nx = gridDim.x, ny = gridDim.y;
  int nwg = nx * ny;
  int orig = blockIdx.y * nx + blockIdx.x;
  int q = nwg >> 3, r = nwg & 7;
  int xcd = orig & 7, loc = orig >> 3;
  int id = (xcd < r ? xcd * (q + 1) : r * (q + 1) + (xcd - r) * q) + loc;
  int bx = id / ny, by = id - bx * ny;
  int n0 = bx * 128, m0 = by * 128;

  int t = threadIdx.x;
  int w = t >> 6, l = t & 63;
  int wm = (w >> 1) * 64, wn = (w & 1) * 64;
  int l15 = l & 15, l4 = l >> 4;

  int srow = w * 16 + (l >> 2);
  int scol = (l & 3) * 8;

  f32x4 acc[4][4] = {};

  auto stage = [&](int buf, int k0) {
    #pragma unroll
    for (int i = 0; i < 2; ++i) {
      gl2lds16(A  + (size_t)(m0 + i * 64 + srow) * K + k0 + scol,
               &lds[buf][0][i * 4096 + w * 1024]);
      gl2lds16(Bt + (size_t)(n0 + i * 64 + srow) * K + k0 + scol,
               &lds[buf][1][i * 4096 + w * 1024]);
    }
  };

  auto compute = [&](int buf) {
    short8 af[4], bfr[4];
    #pragma unroll
    for (int i = 0; i < 4; ++i) {
      af[i]  = *(const short8*)(&lds[buf][0][((wm + i * 16 + l15) * 32 + l4 * 8) * 2]);
      bfr[i] = *(const short8*)(&lds[buf][1][((wn + i * 16 + l15) * 32 + l4 * 8) * 2]);
    }
    #pragma unroll
    for (int i = 0; i < 4; ++i)
      #pragma unroll
      for (int j = 0; j < 4; ++j)
        acc[i][j] = __builtin_amdgcn_mfma_f32_16x16x32_bf16(af[i], bfr[j], acc[i][j], 0, 0, 0);
  };

  int nt = K >> 5;
  int cur = 0;
  stage(0, 0);
  __syncthreads();
  for (int tt = 0; tt < nt; ++tt) {
    if (tt + 1 < nt) stage(cur ^ 1, (tt + 1) * 32);
    compute(cur);
    __syncthreads();
    cur ^= 1;
  }

  #pragma unroll
  for (int i = 0; i < 4; ++i)
    #pragma unroll
    for (int j = 0; j < 4; ++j) {
      int col = n0 + wn + j * 16 + l15;
      #pragma unroll
      for (int rr = 0; rr < 4; ++rr) {
        int row = m0 + wm + i * 16 + l4 * 4 + rr;
        float v = acc[i][j][rr];
        if (MODE == 0) {
          ((bf16u*)C)[(size_t)row * N + col] = f2bf(v);
        } else if (MODE == 1) {
          float* p = (float*)C + (size_t)row * N + col;
          *p += v;
        } else {
          ((float*)C)[(size_t)row * N + col] = v;
        }
      }
    }
}

// ================= 256x256 8-phase GEMM (T1+T2+T3+T4+T5) =================
__device__ __forceinline__ void stage_half(const bf16u* __restrict__ p, int ld,
                                           int row0, int k0, char* slotBase, int t) {
  int r  = t >> 3, c8 = t & 7;
  int cs = (c8 ^ (r & 7)) << 3;
  gl2lds16(p + (size_t)(row0 + r) * ld + k0 + cs, slotBase + t * 16);
  gl2lds16(p + (size_t)(row0 + 64 + r) * ld + k0 + cs, slotBase + 8192 + t * 16);
}

template<int KK>
__device__ __forceinline__ short8 read_frag(const char* slot, int row, int l4) {
  int kc = KK * 4 + l4;
  return *(const short8*)(slot + row * 128 + ((kc ^ (row & 7)) << 4));
}

template<int NH>
__device__ __forceinline__ void mfma_quad(f32x4 (&acc)[8][4], const short8 (&a)[8],
                                          short8 b0, short8 b1) {
  __builtin_amdgcn_s_setprio(1);
  #pragma unroll
  for (int mi = 0; mi < 8; ++mi) {
    acc[mi][NH * 2]     = __builtin_amdgcn_mfma_f32_16x16x32_bf16(a[mi], b0, acc[mi][NH * 2], 0, 0, 0);
    acc[mi][NH * 2 + 1] = __builtin_amdgcn_mfma_f32_16x16x32_bf16(a[mi], b1, acc[mi][NH * 2 + 1], 0, 0, 0);
  }
  __builtin_amdgcn_s_setprio(0);
}

template <int MODE>
__global__ __launch_bounds__(512) void gemm256_kernel(const bf16u* __restrict__ A,
                                                      const bf16u* __restrict__ Bt,
                                                      void* __restrict__ C,
                                                      int M, int N, int K, int ldk) {
  __shared__ __align__(16) char lds[131072];

  int koff = blockIdx.z * K;
  A  += koff;
  Bt += koff;
  float* Cz = (float*)C + (size_t)blockIdx.z * M * N;

  int nx = gridDim.x, ny = gridDim.y;
  int nwg = nx * ny;
  int orig = blockIdx.y * nx + blockIdx.x;
  int q8 = nwg >> 3, r8 = nwg & 7;
  int xcd = orig & 7, loc = orig >> 3;
  int id = (xcd < r8 ? xcd * (q8 + 1) : r8 * (q8 + 1) + (xcd - r8) * q8) + loc;
  int bx = id / ny, by = id - bx * ny;
  int n0 = bx * 256, m0 = by * 256;

  int t = threadIdx.x;
  int wid = t >> 6, lane = t & 63;
  int wr = wid >> 2, wc = wid & 3, bh = wc >> 1;
  int l15 = lane & 15, l4 = lane >> 4;

  char* AS0 = lds;              char* AS1 = lds + 16384;
  char* AS2 = lds + 32768;      char* AS3 = lds + 49152;
  char* BS0 = lds + 65536;      char* BS1 = lds + 81920;
  char* BS2 = lds + 98304;      char* BS3 = lds + 114688;

  const char* ASe = lds + wr * 16384;
  const char* ASo = ASe + 32768;
  const char* BSe = lds + 65536 + bh * 16384;
  const char* BSo = BSe + 32768;

  int brow = (wc & 1) * 64;

  f32x4 acc[8][4] = {};
  short8 a[8];
  short8 b0, b1;

  int NT = K >> 6;
  int NI = NT >> 1;

  stage_half(A,  ldk, m0,       0,  AS0, t);
  stage_half(A,  ldk, m0 + 128, 0,  AS1, t);
  stage_half(Bt, ldk, n0,       0,  BS0, t);
  stage_half(Bt, ldk, n0 + 128, 0,  BS1, t);
  stage_half(A,  ldk, m0,       64, AS2, t);
  asm volatile("s_waitcnt vmcnt(2)" ::: "memory");
  __builtin_amdgcn_s_barrier();
  __builtin_amdgcn_sched_barrier(0);

  for (int I = 0; I < NI; ++I) {
    int t0k = I * 128;
    int t1k = t0k + 64;
    bool notlast = (I + 1 < NI);

    #pragma unroll
    for (int mi = 0; mi < 8; ++mi) a[mi] = read_frag<0>(ASe, mi * 16 + l15, l4);
    b0 = read_frag<0>(BSe, brow + l15, l4);
    b1 = read_frag<0>(BSe, brow + 16 + l15, l4);
    stage_half(A, ldk, m0 + 128, t1k, AS3, t);
    __builtin_amdgcn_s_barrier();
    mfma_quad<0>(acc, a, b0, b1);
    __builtin_amdgcn_s_barrier();

    b0 = read_frag<0>(BSe, brow + 32 + l15, l4);
    b1 = read_frag<0>(BSe, brow + 48 + l15, l4);
    stage_half(Bt, ldk, n0, t1k, BS2, t);
    __builtin_amdgcn_s_barrier();
    mfma_quad<1>(acc, a, b0, b1);
    __builtin_amdgcn_s_barrier();

    #pragma unroll
    for (int mi = 0; mi < 8; ++mi) a[mi] = read_frag<1>(ASe, mi * 16 + l15, l4);
    b0 = read_frag<1>(BSe, brow + l15, l4);
    b1 = read_frag<1>(BSe, brow + 16 + l15, l4);
    stage_half(Bt, ldk, n0 + 128, t1k, BS3, t);
    __builtin_amdgcn_s_barrier();
    mfma_quad<0>(acc, a, b0, b1);
    __builtin_amdgcn_s_barrier();

    b0 = read_frag<1>(BSe, brow + 32 + l15, l4);
    b1 = read_frag<1>(BSe, brow + 48 + l15, l4);
    if (notlast) stage_half(A, ldk, m0, t0k + 128, AS0, t);
    if (notlast) { asm volatile("s_waitcnt vmcnt(2)" ::: "memory"); }
    else         { asm volatile("s_waitcnt vmcnt(0)" ::: "memory"); }
    __builtin_amdgcn_s_barrier();
    __builtin_amdgcn_sched_barrier(0);
    mfma_quad<1>(acc, a, b0, b1);
    __builtin_amdgcn_s_barrier();

    #pragma unroll
    for (int mi = 0; mi < 8; ++mi) a[mi] = read_frag<0>(ASo, mi * 16 + l15, l4);
    b0 = read_frag<0>(BSo, brow + l15, l4);
    b1 = read_frag<0>(BSo, brow + 16 + l15, l4);
    if (notlast) stage_half(A, ldk, m0 + 128, t0k + 128, AS1, t);
    __builtin_amdgcn_s_barrier();
    mfma_quad<0>(acc, a, b0, b1);
    __builtin_amdgcn_s_barrier();

    b0 = read_frag<0>(BSo, brow + 32 + l15, l4);
    b1 = read_frag<0>(BSo, brow + 48 + l15, l4);
    if (notlast) stage_half(Bt, ldk, n0, t0k + 128, BS0, t);
    __builtin_amdgcn_s_barrier();
    mfma_quad<1>(acc, a, b0, b1);
    __builtin_amdgcn_s_barrier();

    #pragma unroll
    for (int mi = 0; mi < 8; ++mi) a[mi] = read_frag<1>(ASo, mi * 16 + l15, l4);
    b0 = read_frag<1>(BSo, brow + l15, l4);
    b1 = read_frag<1>(BSo, brow + 16 + l15, l4);
    if (notlast) stage_half(Bt, ldk, n0 + 128, t0k + 128, BS1, t);
    __builtin_amdgcn_s_barrier();
    mfma_quad<0>(acc, a, b0, b1);
    __builtin_amdgcn_s_barrier();

    b0 = read_frag<1>(BSo, brow + 32 + l15, l4);
    b1 = read_frag<1>(BSo, brow + 48 + l15, l4);
    if (notlast) {
      stage_half(A, ldk, m0, t0k + 192, AS2, t);
      asm volatile("s_waitcnt vmcnt(2)" ::: "memory");
    }
    __builtin_amdgcn_s_barrier();
    __builtin_amdgcn_sched_barrier(0);
    mfma_quad<1>(acc, a, b0, b1);
    __builtin_amdgcn_s_barrier();
  }

  #pragma unroll
  for (int mi = 0; mi < 8; ++mi)
    #pragma unroll
    for (int ni = 0; ni < 4; ++ni) {
      int col = n0 + wc * 64 + ni * 16 + l15;
      #pragma unroll
      for (int rr = 0; rr < 4; ++rr) {
        int row = m0 + wr * 128 + mi * 16 + l4 * 4 + rr;
        float v = acc[mi][ni][rr];
        if (MODE == 3) {
          float pv = __shfl_xor(v, 1);
          if ((l15 & 1) == 0) {
            float hval = pv * (v / (1.0f + __expf(-v)));
            ((bf16u*)C)[(size_t)row * HIDN + (col >> 1)] = f2bf(hval);
          }
        } else if (MODE == 2) {
          Cz[(size_t)row * N + col] = v;
        } else if (MODE == 1) {
          float* p = (float*)C + (size_t)row * N + col;
          *p += v;
        } else {
          ((bf16u*)C)[(size_t)row * N + col] = f2bf(v);
        }
      }
    }
}

// ---------------- sliding-window flash attention (QBLK=128, 8 waves) ----------------
// V is read directly from qkv_bf (row stride QKV_N).
__global__ __launch_bounds__(512) void attn_kernel(const bf16u* __restrict__ q_bf,
                                                   const bf16u* __restrict__ k_bf,
                                                   const bf16u* __restrict__ qkv_bf,
                                                   bf16u* __restrict__ attn_out) {
  int h = blockIdx.y;
  int q0 = blockIdx.x * 128;
  int kvh = h >> 2;
  const bf16u* Kp = k_bf + (size_t)kvh * SEQ * DKH;
  const bf16u* Vp = qkv_bf + 2560 + kvh * DKH;   // [s][QKV_N] strided

  __shared__ __align__(16) char  Klds[64 * 128 * 2];   // swizzled [key][dim]
  __shared__ __align__(16) bf16u Vlds[128][72];        // [dim][key]
  __shared__ __align__(16) bf16u Plds[8][16][72];      // per-wave [qrow][key]

  int t = threadIdx.x, wave = t >> 6, lane = t & 63;
  int l15 = lane & 15, l4 = lane >> 4;
  int qrow0 = q0 + wave * 16;

  short8 qf[4];
  #pragma unroll
  for (int ks = 0; ks < 4; ++ks)
    qf[ks] = *(const short8*)(q_bf + ((size_t)h * SEQ + qrow0 + l15) * DKH + ks * 32 + l4 * 8);

  f32x4 o[8] = {};
  float m[4], lsum[4];
  #pragma unroll
  for (int r = 0; r < 4; ++r) { m[r] = -INFINITY; lsum[r] = 0.0f; }

  int vkey = t & 63, vd0 = (t >> 6) * 16;

  int jstart = q0 >= WIN ? ((q0 - (WIN - 1)) & ~63) : 0;

  for (int j0 = jstart; j0 < q0 + 128; j0 += 64) {
    __syncthreads();
    #pragma unroll
    for (int i = 0; i < 2; ++i) {
      int c = t + i * 512;
      int key = c >> 4, cc = c & 15;
      int off = key * 256 + cc * 16; off ^= (key & 7) << 4;
      *(short8*)(Klds + off) = *(const short8*)(Kp + (size_t)(j0 + key) * DKH + cc * 8);
    }
    {
      const bf16u* src = Vp + (size_t)(j0 + vkey) * QKV_N + vd0;
      short8 v0 = *(const short8*)(src);
      short8 v1 = *(const short8*)(src + 8);
      #pragma unroll
      for (int i = 0; i < 8; ++i) Vlds[vd0 + i][vkey] = (bf16u)(unsigned short)v0[i];
      #pragma unroll
      for (int i = 0; i < 8; ++i) Vlds[vd0 + 8 + i][vkey] = (bf16u)(unsigned short)v1[i];
    }
    __syncthreads();

    f32x4 sacc[4] = {};
    #pragma unroll
    for (int nt = 0; nt < 4; ++nt) {
      int key = nt * 16 + l15;
      #pragma unroll
      for (int ks = 0; ks < 4; ++ks) {
        int off = key * 256 + ks * 64 + l4 * 16; off ^= (key & 7) << 4;
        short8 kf = *(short8*)(Klds + off);
        sacc[nt] = __builtin_amdgcn_mfma_f32_16x16x32_bf16(qf[ks], kf, sacc[nt], 0, 0, 0);
      }
    }

    float sv[4][4];
    #pragma unroll
    for (int nt = 0; nt < 4; ++nt) {
      int jk = j0 + nt * 16 + l15;
      #pragma unroll
      for (int r = 0; r < 4; ++r) {
        int iq = qrow0 + l4 * 4 + r;
        float s = sacc[nt][r] * 0.08838834764831845f;
        bool valid = (jk <= iq) && (iq - jk < WIN);
        sv[nt][r] = valid ? s : -1e9f;
      }
    }

    float mxr[4];
    #pragma unroll
    for (int r = 0; r < 4; ++r) {
      float mx = fmaxf(fmaxf(sv[0][r], sv[1][r]), fmaxf(sv[2][r], sv[3][r]));
      #pragma unroll
      for (int off = 1; off < 16; off <<= 1) mx = fmaxf(mx, __shfl_xor(mx, off));
      mxr[r] = mx;
    }

    bool grow = (mxr[0] > m[0] + 8.0f) || (mxr[1] > m[1] + 8.0f) ||
                (mxr[2] > m[2] + 8.0f) || (mxr[3] > m[3] + 8.0f);
    if (__any(grow)) {
      #pragma unroll
      for (int r = 0; r < 4; ++r) {
        float mn = fmaxf(m[r], mxr[r]);
        float alpha = __expf(m[r] - mn);
        m[r] = mn;
        lsum[r] *= alpha;
        #pragma unroll
        for (int d = 0; d < 8; ++d) o[d][r] *= alpha;
      }
    }

    float p[4][4];
    #pragma unroll
    for (int r = 0; r < 4; ++r) {
      float ps = 0.0f;
      #pragma unroll
      for (int nt = 0; nt < 4; ++nt) { p[nt][r] = __expf(sv[nt][r] - m[r]); ps += p[nt][r]; }
      #pragma unroll
      for (int off = 1; off < 16; off <<= 1) ps += __shfl_xor(ps, off);
      lsum[r] += ps;
    }

    #pragma unroll
    for (int nt = 0; nt < 4; ++nt)
      #pragma unroll
      for (int r = 0; r < 4; ++r)
        Plds[wave][l4 * 4 + r][nt * 16 + l15] = f2bf(p[nt][r]);

    #pragma unroll
    for (int kk = 0; kk < 2; ++kk) {
      short8 pf = *(short8*)(&Plds[wave][l15][kk * 32 + l4 * 8]);
      #pragma unroll
      for (int d = 0; d < 8; ++d) {
        short8 vf = *(short8*)(&Vlds[d * 16 + l15][kk * 32 + l4 * 8]);
        o[d] = __builtin_amdgcn_mfma_f32_16x16x32_bf16(pf, vf, o[d], 0, 0, 0);
      }
    }
  }

  #pragma unroll
  for (int d = 0; d < 8; ++d)
    #pragma unroll
    for (int r = 0; r < 4; ++r) {
      int row = qrow0 + l4 * 4 + r;
      attn_out[(size_t)row * (NHEAD * DKH) + h * DKH + d * 16 + l15] = f2bf(o[d][r] / lsum[r]);
    }
}

// ---------------- host ----------------
extern "C" void kernel_launch(void* const* d_in, const int* in_sizes, int n_in,
                              void* d_out, int out_size, void* d_ws, size_t ws_size,
                              hipStream_t stream) {
  const int*   tokens  = (const int*)d_in[0];
  const float* table   = (const float*)d_in[1];
  const float* wq      = (const float*)d_in[2];
  const float* wk      = (const float*)d_in[3];
  const float* wv      = (const float*)d_in[4];
  const float* wo      = (const float*)d_in[5];
  const float* w_up    = (const float*)d_in[6];
  const float* w_down  = (const float*)d_in[7];
  const float* w_vocab = (const float*)d_in[8];
  float* out = (float*)d_out;

  char* base = (char*)d_ws;
  size_t o = 0;
  auto alloc = [&](size_t bytes) { size_t r = o; o += (bytes + 255) & ~(size_t)255; return r; };
  size_t o_x     = alloc((size_t)SEQ * EMB * 4);
  size_t o_nbf   = alloc((size_t)SEQ * EMB * 2);
  size_t o_qkvw  = alloc((size_t)NLAY * QKV_N * EMB * 2);
  size_t o_wot   = alloc((size_t)NLAY * EMB * EMB * 2);
  size_t o_wupt  = alloc((size_t)NLAY * 2 * HIDN * EMB * 2);
  size_t o_wdnt  = alloc((size_t)NLAY * EMB * HIDN * 2);
  size_t o_qkvbf = alloc((size_t)SEQ * QKV_N * 2);
  size_t o_qbf   = alloc((size_t)NHEAD * SEQ * DKH * 2);
  size_t o_kbf   = alloc((size_t)NKV * SEQ * DKH * 2);
  size_t o_attn  = alloc((size_t)SEQ * EMB * 2);
  size_t o_big   = alloc((size_t)SEQ * 2 * HIDN * 4);   // split-K partials / wvoc_t
  size_t o_hbf   = alloc((size_t)SEQ * HIDN * 2);

  float* x      = (float*)(base + o_x);
  bf16u* n_bf   = (bf16u*)(base + o_nbf);
  bf16u* qkvw_t = (bf16u*)(base + o_qkvw);
  bf16u* wo_t   = (bf16u*)(base + o_wot);
  bf16u* wup_t  = (bf16u*)(base + o_wupt);
  bf16u* wdn_t  = (bf16u*)(base + o_wdnt);
  bf16u* qkv_bf = (bf16u*)(base + o_qkvbf);
  bf16u* q_bf   = (bf16u*)(base + o_qbf);
  bf16u* k_bf   = (bf16u*)(base + o_kbf);
  bf16u* attn_b = (bf16u*)(base + o_attn);
  float* part   = (float*)(base + o_big);
  bf16u* h_bf   = (bf16u*)(base + o_hbf);
  bf16u* wvoc_t = (bf16u*)(base + o_big);

  const size_t QKVW = (size_t)QKV_N * EMB;

  // ---- batched weight transposes (all layers at once) ----
  transp_kernel<<<dim3(EMB / 64, EMB / 64, NLAY), 256, 0, stream>>>(
      wq, qkvw_t, EMB, EMB, 0, QKVW);
  transp_kernel<<<dim3(512 / 64, EMB / 64, NLAY), 256, 0, stream>>>(
      wk, qkvw_t + (size_t)2048 * EMB, EMB, 512, 0, QKVW);
  transp_kernel<<<dim3(512 / 64, EMB / 64, NLAY), 256, 0, stream>>>(
      wv, qkvw_t + (size_t)2560 * EMB, EMB, 512, 0, QKVW);
  transp_kernel<<<dim3(EMB / 64, EMB / 64, NLAY), 256, 0, stream>>>(
      wo, wo_t, EMB, EMB, 0, (size_t)EMB * EMB);
  transp_kernel<<<dim3(2 * HIDN / 64, EMB / 64, NLAY), 256, 0, stream>>>(
      w_up, wup_t, EMB, 2 * HIDN, HIDN, (size_t)2 * HIDN * EMB);
  transp_kernel<<<dim3(EMB / 64, HIDN / 64, NLAY), 256, 0, stream>>>(
      w_down, wdn_t, HIDN, EMB, 0, (size_t)EMB * HIDN);

  embed_kernel<<<SEQ, 256, 0, stream>>>(tokens, table, x);
  rmsnorm_kernel<<<SEQ, 256, 0, stream>>>(x, n_bf);

  for (int l = 0; l < NLAY; ++l) {
    gemm_kernel<0><<<dim3(QKV_N / 128, SEQ / 128), 256, 0, stream>>>(
        n_bf, qkvw_t + (size_t)l * QKVW, qkv_bf, SEQ, QKV_N, EMB);

    rope_kernel<<<(NHEAD + NKV) * SEQ * 64 / 256, 256, 0, stream>>>(qkv_bf, q_bf, k_bf);

    attn_kernel<<<dim3(SEQ / 128, NHEAD), 512, 0, stream>>>(q_bf, k_bf, qkv_bf, attn_b);

    gemm_kernel<1><<<dim3(EMB / 128, SEQ / 128), 256, 0, stream>>>(
        attn_b, wo_t + (size_t)l * EMB * EMB, x, SEQ, EMB, EMB);

    rmsnorm_kernel<<<SEQ, 256, 0, stream>>>(x, n_bf);
    gemm256_kernel<3><<<dim3(2 * HIDN / 256, SEQ / 256), 512, 0, stream>>>(
        n_bf, wup_t + (size_t)l * 2 * HIDN * EMB, h_bf, SEQ, 2 * HIDN, EMB, EMB);
    gemm256_kernel<2><<<dim3(EMB / 256, SEQ / 256, 4), 512, 0, stream>>>(
        h_bf, wdn_t + (size_t)l * EMB * HIDN, part, SEQ, EMB, 2048, HIDN);
    reduce4norm_kernel<<<SEQ, 256, 0, stream>>>(x, part, n_bf);
  }

  transp_kernel<<<dim3(NVOC / 64, EMB / 64, 1), 256, 0, stream>>>(
      w_vocab, wvoc_t, EMB, NVOC, 0, 0);
  gemm256_kernel<2><<<dim3(NVOC / 256, SEQ / 256), 512, 0, stream>>>(
      n_bf, wvoc_t, out, SEQ, NVOC, EMB, EMB);
}